// Round 2
// baseline (787.356 us; speedup 1.0000x reference)
//
#include <hip/hip_runtime.h>
#include <math.h>

#define NTOK 4096
#define IND 768
#define DD 256
#define DD2 512
#define DD4 64
#define DHH 128
#define NEXP 51

__device__ __forceinline__ float gelu_f(float x) {
    return 0.5f * x * (1.0f + erff(x * 0.70710678118654752440f));
}

// block-wide sum for 256 threads (4 waves); lds must have >= 4 floats
__device__ __forceinline__ float block_sum(float v, float* lds) {
    #pragma unroll
    for (int o = 32; o > 0; o >>= 1) v += __shfl_down(v, o);
    int lane = threadIdx.x & 63, w = threadIdx.x >> 6;
    if (lane == 0) lds[w] = v;
    __syncthreads();
    float r = lds[0] + lds[1] + lds[2] + lds[3];
    __syncthreads();
    return r;
}

// ---- kernel 0: token-independent spatial_feat / level_feat ----
__global__ __launch_bounds__(64) void k_const(
    const float* __restrict__ spw1, const float* __restrict__ spb1,
    const float* __restrict__ spw2, const float* __restrict__ spb2,
    const float* __restrict__ lw1, const float* __restrict__ lb1,
    const float* __restrict__ lw2, const float* __restrict__ lb2,
    const int* __restrict__ levels, const int* __restrict__ ph, const int* __restrict__ pw,
    float* __restrict__ constf) {
    __shared__ float hs[64], hl[64];
    int t = threadIdx.x;
    float p0 = (float)ph[0], p1 = (float)pw[0];
    float lvl = (float)levels[0];
    hs[t] = fmaxf(0.f, p0 * spw1[t] + p1 * spw1[64 + t] + spb1[t]);
    hl[t] = fmaxf(0.f, lvl * lw1[t] + lb1[t]);
    __syncthreads();
    float a = spb2[t], b = lb2[t];
    for (int j = 0; j < 64; ++j) {
        a += hs[j] * spw2[j * 64 + t];
        b += hl[j] * lw2[j * 64 + t];
    }
    constf[t] = a;
    constf[64 + t] = b;
}

// ---- kernel A: per-token LN, stats, edge, stats/edge MLPs, enh_in assembly ----
__global__ __launch_bounds__(256) void k_stats(
    const float* __restrict__ tokens,
    const float* __restrict__ ln_g, const float* __restrict__ ln_b,
    const float* __restrict__ sw1, const float* __restrict__ sb1,
    const float* __restrict__ sw2, const float* __restrict__ sb2,
    const float* __restrict__ ew1, const float* __restrict__ eb1,
    const float* __restrict__ ew2, const float* __restrict__ eb2,
    const float* __restrict__ constf,
    float* __restrict__ x_ln, float* __restrict__ enh_in) {
    int n = blockIdx.x, t = threadIdx.x;
    const float* x = tokens + (size_t)n * IND;
    __shared__ float red[4];
    float v[3];
    float s = 0.f, s2 = 0.f, es = 0.f;
    #pragma unroll
    for (int i = 0; i < 3; ++i) {
        int e = t + i * 256;
        float xv = x[e];
        v[i] = xv;
        s += xv; s2 += xv * xv;
        if (e > 0) es += fabsf(xv - x[e - 1]);
    }
    s  = block_sum(s, red);
    s2 = block_sum(s2, red);
    es = block_sum(es, red);
    float mean = s * (1.f / 768.f);
    float var_b = s2 * (1.f / 768.f) - mean * mean;
    float var_u = (s2 - 768.f * mean * mean) * (1.f / 767.f);
    float rstd = rsqrtf(var_b + 1e-5f);
    float edge = es * (1.f / 767.f);
    #pragma unroll
    for (int i = 0; i < 3; ++i) {
        int e = t + i * 256;
        x_ln[(size_t)n * IND + e] = (v[i] - mean) * rstd * ln_g[e] + ln_b[e];
    }
    __shared__ float hid[128];
    if (t < 64) {
        hid[t] = fmaxf(0.f, var_u * sw1[t] + mean * sw1[64 + t] + sb1[t]);
    } else if (t < 128) {
        int j = t - 64;
        hid[64 + j] = fmaxf(0.f, edge * ew1[j] + eb1[j]);
    }
    __syncthreads();
    float* er = enh_in + (size_t)n * DD;
    if (t < 64) {
        float a = sb2[t];
        for (int j = 0; j < 64; ++j) a += hid[j] * sw2[j * 64 + t];
        er[t] = a;
    } else if (t < 128) {
        int k = t - 64;
        float a = eb2[k];
        for (int j = 0; j < 64; ++j) a += hid[64 + j] * ew2[j * 64 + k];
        er[64 + k] = a;
    } else {
        er[t] = constf[t - 128];
    }
}

// ---- tiled fp32 GEMM: C[M,N] = A[M,K] @ B[K,N] + bias; epi 0=none 1=gelu 2=+emb[idx] ----
__global__ __launch_bounds__(256) void k_gemm(
    const float* __restrict__ A, const float* __restrict__ B,
    const float* __restrict__ bias, float* __restrict__ C,
    int M, int N, int K, int epi,
    const int* __restrict__ levels, const float* __restrict__ emb) {
    __shared__ float As[16][64];
    __shared__ float Bs[16][64];
    int tid = threadIdx.x;
    int bm = blockIdx.y * 64, bn = blockIdx.x * 64;
    int tx = tid & 15, ty = tid >> 4;
    float acc[4][4] = {};
    for (int k0 = 0; k0 < K; k0 += 16) {
        {
            int r = tid >> 2, c4 = (tid & 3) * 4;
            float4 av = *(const float4*)(A + (size_t)(bm + r) * K + k0 + c4);
            As[c4 + 0][r] = av.x; As[c4 + 1][r] = av.y;
            As[c4 + 2][r] = av.z; As[c4 + 3][r] = av.w;
        }
        {
            int rb = tid >> 4, cb = (tid & 15) * 4;
            *(float4*)&Bs[rb][cb] = *(const float4*)(B + (size_t)(k0 + rb) * N + bn + cb);
        }
        __syncthreads();
        #pragma unroll
        for (int k = 0; k < 16; ++k) {
            float4 a4 = *(const float4*)&As[k][ty * 4];
            float4 b4 = *(const float4*)&Bs[k][tx * 4];
            float a[4] = {a4.x, a4.y, a4.z, a4.w};
            float b[4] = {b4.x, b4.y, b4.z, b4.w};
            #pragma unroll
            for (int i = 0; i < 4; ++i)
                #pragma unroll
                for (int j = 0; j < 4; ++j)
                    acc[i][j] += a[i] * b[j];
        }
        __syncthreads();
    }
    #pragma unroll
    for (int i = 0; i < 4; ++i) {
        int m = bm + ty * 4 + i;
        #pragma unroll
        for (int j = 0; j < 4; ++j) {
            int n = bn + tx * 4 + j;
            float vv = acc[i][j] + bias[n];
            if (epi == 1) {
                vv = gelu_f(vv);
            } else if (epi == 2) {
                int id = min(max(levels[m * 2], 0), 50);
                vv += emb[(size_t)id * N + n];
            }
            C[(size_t)m * N + n] = vv;
        }
    }
}

// ---- expert grouping: histogram + prefix + scatter, single block ----
__global__ __launch_bounds__(1024) void k_group(
    const int* __restrict__ levels, int* __restrict__ sorted, int* __restrict__ off) {
    __shared__ int cnt[NEXP], cur[NEXP];
    int t = threadIdx.x;
    if (t < NEXP) cnt[t] = 0;
    __syncthreads();
    int myidx[4];
    #pragma unroll
    for (int i = 0; i < 4; ++i) {
        int n = t + i * 1024;
        int id = min(max(levels[n * 2], 0), 50);
        myidx[i] = id;
        atomicAdd(&cnt[id], 1);
    }
    __syncthreads();
    if (t == 0) {
        int acc = 0;
        for (int e = 0; e < NEXP; ++e) { off[e] = acc; cur[e] = acc; acc += cnt[e]; }
        off[NEXP] = acc;
    }
    __syncthreads();
    #pragma unroll
    for (int i = 0; i < 4; ++i) {
        int n = t + i * 1024;
        int p = atomicAdd(&cur[myidx[i]], 1);
        sorted[p] = n;
    }
}

// ---- grouped expert adapter: enh-LN fold + y = hfull@aW[e]+ab, LN+gelu, gate, scatter ----
__global__ __launch_bounds__(256) void k_egemm(
    const float* __restrict__ h, const float* __restrict__ e_pre,
    const float* __restrict__ fg, const float* __restrict__ fbeta,
    const float* __restrict__ aW, const float* __restrict__ ab,
    const float* __restrict__ ag, const float* __restrict__ abt,
    const float* __restrict__ dw1, const float* __restrict__ db1,
    const float* __restrict__ dw2, const float* __restrict__ db2,
    const int* __restrict__ sorted, const int* __restrict__ off,
    float* __restrict__ out) {
    int e = blockIdx.y;
    int o0 = off[e];
    int cnt = off[e + 1] - o0;
    int row0 = (int)blockIdx.x * 64;
    if (row0 >= cnt) return;
    int nrow = min(64, cnt - row0);

    __shared__ float ys[64][260];   // hfull during GEMM, then y
    __shared__ float Bs[16][256];   // aW tile
    __shared__ int tokS[64];
    __shared__ float gateS[64];

    int tid = threadIdx.x;
    if (tid < 64) tokS[tid] = sorted[o0 + row0 + min(tid, nrow - 1)];
    __syncthreads();

    int wv = tid >> 6, ln = tid & 63;
    // ---- phase 1: hfull = h + 0.3*gelu(LN(e_pre; fg,fbeta)), one row per wave-pass ----
    for (int t = 0; t < 16; ++t) {
        int r = (t << 2) + wv;
        int tok = tokS[r];
        float4 e4 = *(const float4*)(e_pre + (size_t)tok * DD + ln * 4);
        float ev[4] = {e4.x, e4.y, e4.z, e4.w};
        float s = 0.f, s2 = 0.f;
        #pragma unroll
        for (int j = 0; j < 4; ++j) { s += ev[j]; s2 += ev[j] * ev[j]; }
        #pragma unroll
        for (int o = 1; o < 64; o <<= 1) { s += __shfl_xor(s, o); s2 += __shfl_xor(s2, o); }
        float m = s * (1.f / 256.f);
        float va = s2 * (1.f / 256.f) - m * m;
        float rs = rsqrtf(va + 1e-5f);
        float4 h4 = *(const float4*)(h + (size_t)tok * DD + ln * 4);
        float hv[4] = {h4.x, h4.y, h4.z, h4.w};
        #pragma unroll
        for (int j = 0; j < 4; ++j) {
            int c = ln * 4 + j;
            float enh = gelu_f((ev[j] - m) * rs * fg[c] + fbeta[c]);
            ys[r][c] = hv[j] + 0.3f * enh;
        }
    }
    __syncthreads();

    // ---- phase 2: GEMM  acc[64 rows x 256 cols] = hfull @ aW[e] ----
    const float* W = aW + (size_t)e * DD * DD;
    int ty = tid >> 4, tx = tid & 15;
    float acc[4][16] = {};
    for (int k0 = 0; k0 < DD; k0 += 16) {
        {
            int rb = tid >> 4, cb = (tid & 15) * 16;
            const float4* src = (const float4*)(W + (size_t)(k0 + rb) * DD + cb);
            float4* dst = (float4*)&Bs[rb][cb];
            dst[0] = src[0]; dst[1] = src[1]; dst[2] = src[2]; dst[3] = src[3];
        }
        __syncthreads();
        #pragma unroll
        for (int kk = 0; kk < 16; ++kk) {
            int k = k0 + kk;
            float a[4];
            #pragma unroll
            for (int i = 0; i < 4; ++i) a[i] = ys[(ty << 2) + i][k];
            #pragma unroll
            for (int j = 0; j < 4; ++j) {
                // thread cols: c = tx*4 + j*64 + jj  (contiguous across lanes -> no LDS conflicts)
                float4 b4 = *(const float4*)&Bs[kk][(tx << 2) + (j << 6)];
                float b[4] = {b4.x, b4.y, b4.z, b4.w};
                #pragma unroll
                for (int i = 0; i < 4; ++i) {
                    #pragma unroll
                    for (int jj = 0; jj < 4; ++jj)
                        acc[i][(j << 2) + jj] += a[i] * b[jj];
                }
            }
        }
        __syncthreads();
    }

    // ---- phase 3: y_pre = acc + ab[e]  (overwrite ys; all reads of hfull done) ----
    const float* abp = ab + (size_t)e * DD;
    #pragma unroll
    for (int i = 0; i < 4; ++i) {
        int r = (ty << 2) + i;
        #pragma unroll
        for (int j = 0; j < 4; ++j) {
            #pragma unroll
            for (int jj = 0; jj < 4; ++jj) {
                int c = (tx << 2) + (j << 6) + jj;
                ys[r][c] = acc[i][(j << 2) + jj] + abp[c];
            }
        }
    }
    __syncthreads();

    // ---- phase 4: per-row LN (ag,abt) + gelu, in place ----
    const float* agp = ag + (size_t)e * DD;
    const float* abtp = abt + (size_t)e * DD;
    for (int t = 0; t < 16; ++t) {
        int r = (t << 2) + wv;
        float4 y4 = *(const float4*)&ys[r][ln * 4];
        float yv[4] = {y4.x, y4.y, y4.z, y4.w};
        float s = 0.f, s2 = 0.f;
        #pragma unroll
        for (int j = 0; j < 4; ++j) { s += yv[j]; s2 += yv[j] * yv[j]; }
        #pragma unroll
        for (int o = 1; o < 64; o <<= 1) { s += __shfl_xor(s, o); s2 += __shfl_xor(s2, o); }
        float m = s * (1.f / 256.f);
        float va = s2 * (1.f / 256.f) - m * m;
        float rs = rsqrtf(va + 1e-5f);
        #pragma unroll
        for (int j = 0; j < 4; ++j) {
            int c = ln * 4 + j;
            ys[r][c] = gelu_f((yv[j] - m) * rs * agp[c] + abtp[c]);
        }
    }
    __syncthreads();

    // ---- phase 5: gate = sigmoid(relu(y@dw1+db1)@dw2+db2), rows ty*4+i, cols tx*2+32j+{0,1} ----
    float hv[4][8];
    #pragma unroll
    for (int i = 0; i < 4; ++i)
        #pragma unroll
        for (int jc = 0; jc < 8; ++jc) {
            int c = (tx << 1) + ((jc >> 1) << 5) + (jc & 1);
            hv[i][jc] = db1[c];
        }
    for (int d = 0; d < DD; ++d) {
        float a[4];
        #pragma unroll
        for (int i = 0; i < 4; ++i) a[i] = ys[(ty << 2) + i][d];
        #pragma unroll
        for (int j = 0; j < 4; ++j) {
            float2 w2 = *(const float2*)(dw1 + (size_t)d * DHH + (tx << 1) + (j << 5));
            #pragma unroll
            for (int i = 0; i < 4; ++i) {
                hv[i][j * 2 + 0] += a[i] * w2.x;
                hv[i][j * 2 + 1] += a[i] * w2.y;
            }
        }
    }
    #pragma unroll
    for (int i = 0; i < 4; ++i) {
        float p = 0.f;
        #pragma unroll
        for (int jc = 0; jc < 8; ++jc) {
            int c = (tx << 1) + ((jc >> 1) << 5) + (jc & 1);
            p += fmaxf(hv[i][jc], 0.f) * dw2[c];
        }
        #pragma unroll
        for (int o = 1; o < 16; o <<= 1) p += __shfl_xor(p, o);
        if (tx == 0)
            gateS[(ty << 2) + i] = 0.8f + 0.4f / (1.f + expf(-(p + db2[0])));
    }
    __syncthreads();

    // ---- phase 6: scatter out = y * gate ----
    for (int t = 0; t < 16; ++t) {
        int r = (t << 2) + wv;
        if (r < nrow) {
            int tok = tokS[r];
            float g = gateS[r];
            float4 y4 = *(const float4*)&ys[r][ln * 4];
            y4.x *= g; y4.y *= g; y4.z *= g; y4.w *= g;
            *(float4*)(out + (size_t)tok * DD + ln * 4) = y4;
        }
    }
}

extern "C" void kernel_launch(void* const* d_in, const int* in_sizes, int n_in,
                              void* d_out, int out_size, void* d_ws, size_t ws_size,
                              hipStream_t stream) {
    const float* tokens = (const float*)d_in[0];
    const float* ln_g = (const float*)d_in[1];
    const float* ln_b = (const float*)d_in[2];
    const float* pw1 = (const float*)d_in[3];
    const float* pb1 = (const float*)d_in[4];
    const float* pw2 = (const float*)d_in[5];
    const float* pb2 = (const float*)d_in[6];
    const float* emb = (const float*)d_in[7];
    const float* sw1 = (const float*)d_in[8];
    const float* sb1 = (const float*)d_in[9];
    const float* sw2 = (const float*)d_in[10];
    const float* sb2 = (const float*)d_in[11];
    const float* ew1 = (const float*)d_in[12];
    const float* eb1 = (const float*)d_in[13];
    const float* ew2 = (const float*)d_in[14];
    const float* eb2 = (const float*)d_in[15];
    const float* spw1 = (const float*)d_in[16];
    const float* spb1 = (const float*)d_in[17];
    const float* spw2 = (const float*)d_in[18];
    const float* spb2 = (const float*)d_in[19];
    const float* lw1 = (const float*)d_in[20];
    const float* lb1 = (const float*)d_in[21];
    const float* lw2 = (const float*)d_in[22];
    const float* lb2 = (const float*)d_in[23];
    const float* fw = (const float*)d_in[24];
    const float* fb = (const float*)d_in[25];
    const float* fg = (const float*)d_in[26];
    const float* fbeta = (const float*)d_in[27];
    const float* aW = (const float*)d_in[28];
    const float* ab = (const float*)d_in[29];
    const float* ag = (const float*)d_in[30];
    const float* abt = (const float*)d_in[31];
    const float* dw1 = (const float*)d_in[32];
    const float* db1 = (const float*)d_in[33];
    const float* dw2 = (const float*)d_in[34];
    const float* db2 = (const float*)d_in[35];
    const int* levels = (const int*)d_in[36];
    const int* ph = (const int*)d_in[37];
    const int* pw = (const int*)d_in[38];
    float* outp = (float*)d_out;

    float* ws = (float*)d_ws;
    float* x_ln  = ws;                               // 4096*768
    float* h1    = x_ln + (size_t)NTOK * IND;        // 4096*512
    float* h     = h1 + (size_t)NTOK * DD2;          // 4096*256
    float* enh_in = h + (size_t)NTOK * DD;           // 4096*256
    float* e_pre = enh_in + (size_t)NTOK * DD;       // 4096*256
    float* constf = e_pre + (size_t)NTOK * DD;       // 128
    int* sorted = (int*)(constf + 128);              // 4096
    int* off    = sorted + NTOK;                     // 52

    k_const<<<1, 64, 0, stream>>>(spw1, spb1, spw2, spb2, lw1, lb1, lw2, lb2,
                                  levels, ph, pw, constf);
    k_group<<<1, 1024, 0, stream>>>(levels, sorted, off);
    k_stats<<<NTOK, 256, 0, stream>>>(tokens, ln_g, ln_b, sw1, sb1, sw2, sb2,
                                      ew1, eb1, ew2, eb2, constf, x_ln, enh_in);
    k_gemm<<<dim3(DD2 / 64, NTOK / 64), 256, 0, stream>>>(
        x_ln, pw1, pb1, h1, NTOK, DD2, IND, 1, nullptr, nullptr);
    k_gemm<<<dim3(DD / 64, NTOK / 64), 256, 0, stream>>>(
        h1, pw2, pb2, h, NTOK, DD, DD2, 2, levels, emb);
    k_gemm<<<dim3(DD / 64, NTOK / 64), 256, 0, stream>>>(
        enh_in, fw, fb, e_pre, NTOK, DD, DD, 0, nullptr, nullptr);
    k_egemm<<<dim3(64, NEXP), 256, 0, stream>>>(
        h, e_pre, fg, fbeta, aW, ab, ag, abt,
        dw1, db1, dw2, db2, sorted, off, outp);
}

// Round 3
// 197.233 us; speedup vs baseline: 3.9920x; 3.9920x over previous
//
#include <hip/hip_runtime.h>
#include <math.h>

#define NTOK 4096
#define IND 768
#define DD 256
#define DD2 512
#define DD4 64
#define DHH 128
#define NEXP 51

__device__ __forceinline__ float gelu_f(float x) {
    return 0.5f * x * (1.0f + erff(x * 0.70710678118654752440f));
}

// block-wide sum for 256 threads (4 waves); lds must have >= 4 floats
__device__ __forceinline__ float block_sum(float v, float* lds) {
    #pragma unroll
    for (int o = 32; o > 0; o >>= 1) v += __shfl_down(v, o);
    int lane = threadIdx.x & 63, w = threadIdx.x >> 6;
    if (lane == 0) lds[w] = v;
    __syncthreads();
    float r = lds[0] + lds[1] + lds[2] + lds[3];
    __syncthreads();
    return r;
}

// ---- kernel 0: token-independent spatial_feat / level_feat ----
__global__ __launch_bounds__(64) void k_const(
    const float* __restrict__ spw1, const float* __restrict__ spb1,
    const float* __restrict__ spw2, const float* __restrict__ spb2,
    const float* __restrict__ lw1, const float* __restrict__ lb1,
    const float* __restrict__ lw2, const float* __restrict__ lb2,
    const int* __restrict__ levels, const int* __restrict__ ph, const int* __restrict__ pw,
    float* __restrict__ constf) {
    __shared__ float hs[64], hl[64];
    int t = threadIdx.x;
    float p0 = (float)ph[0], p1 = (float)pw[0];
    float lvl = (float)levels[0];
    hs[t] = fmaxf(0.f, p0 * spw1[t] + p1 * spw1[64 + t] + spb1[t]);
    hl[t] = fmaxf(0.f, lvl * lw1[t] + lb1[t]);
    __syncthreads();
    float a = spb2[t], b = lb2[t];
    for (int j = 0; j < 64; ++j) {
        a += hs[j] * spw2[j * 64 + t];
        b += hl[j] * lw2[j * 64 + t];
    }
    constf[t] = a;
    constf[64 + t] = b;
}

// ---- expert grouping: histogram + prefix + scatter, single block ----
__global__ __launch_bounds__(1024) void k_group(
    const int* __restrict__ levels, int* __restrict__ sorted, int* __restrict__ off) {
    __shared__ int cnt[NEXP], cur[NEXP];
    int t = threadIdx.x;
    if (t < NEXP) cnt[t] = 0;
    __syncthreads();
    int myidx[4];
    #pragma unroll
    for (int i = 0; i < 4; ++i) {
        int n = t + i * 1024;
        int id = min(max(levels[n * 2], 0), 50);
        myidx[i] = id;
        atomicAdd(&cnt[id], 1);
    }
    __syncthreads();
    if (t == 0) {
        int acc = 0;
        for (int e = 0; e < NEXP; ++e) { off[e] = acc; cur[e] = acc; acc += cnt[e]; }
        off[NEXP] = acc;
    }
    __syncthreads();
    #pragma unroll
    for (int i = 0; i < 4; ++i) {
        int n = t + i * 1024;
        int p = atomicAdd(&cur[myidx[i]], 1);
        sorted[p] = n;
    }
}

// ---- kernel A: per-token LN, stats, edge, stats/edge MLPs, enh_in assembly ----
__global__ __launch_bounds__(256) void k_stats(
    const float* __restrict__ tokens,
    const float* __restrict__ ln_g, const float* __restrict__ ln_b,
    const float* __restrict__ sw1, const float* __restrict__ sb1,
    const float* __restrict__ sw2, const float* __restrict__ sb2,
    const float* __restrict__ ew1, const float* __restrict__ eb1,
    const float* __restrict__ ew2, const float* __restrict__ eb2,
    const float* __restrict__ constf,
    float* __restrict__ x_ln, float* __restrict__ enh_in) {
    int n = blockIdx.x, t = threadIdx.x;
    const float* x = tokens + (size_t)n * IND;
    __shared__ float red[4];
    float v[3];
    float s = 0.f, s2 = 0.f, es = 0.f;
    #pragma unroll
    for (int i = 0; i < 3; ++i) {
        int e = t + i * 256;
        float xv = x[e];
        v[i] = xv;
        s += xv; s2 += xv * xv;
        if (e > 0) es += fabsf(xv - x[e - 1]);
    }
    s  = block_sum(s, red);
    s2 = block_sum(s2, red);
    es = block_sum(es, red);
    float mean = s * (1.f / 768.f);
    float var_b = s2 * (1.f / 768.f) - mean * mean;
    float var_u = (s2 - 768.f * mean * mean) * (1.f / 767.f);
    float rstd = rsqrtf(var_b + 1e-5f);
    float edge = es * (1.f / 767.f);
    #pragma unroll
    for (int i = 0; i < 3; ++i) {
        int e = t + i * 256;
        x_ln[(size_t)n * IND + e] = (v[i] - mean) * rstd * ln_g[e] + ln_b[e];
    }
    __shared__ float hid[128];
    if (t < 64) {
        hid[t] = fmaxf(0.f, var_u * sw1[t] + mean * sw1[64 + t] + sb1[t]);
    } else if (t < 128) {
        int j = t - 64;
        hid[64 + j] = fmaxf(0.f, edge * ew1[j] + eb1[j]);
    }
    __syncthreads();
    float* er = enh_in + (size_t)n * DD;
    if (t < 64) {
        float a = sb2[t];
        for (int j = 0; j < 64; ++j) a += hid[j] * sw2[j * 64 + t];
        er[t] = a;
    } else if (t < 128) {
        int k = t - 64;
        float a = eb2[k];
        for (int j = 0; j < 64; ++j) a += hid[64 + j] * ew2[j * 64 + k];
        er[64 + k] = a;
    } else {
        er[t] = constf[t - 128];
    }
}

// ---- tiled fp32 GEMM: C[M,N] = A[M,K] @ B[K,N] + bias; epi 0=none 1=gelu 2=+emb[idx] ----
__global__ __launch_bounds__(256) void k_gemm(
    const float* __restrict__ A, const float* __restrict__ B,
    const float* __restrict__ bias, float* __restrict__ C,
    int M, int N, int K, int epi,
    const int* __restrict__ levels, const float* __restrict__ emb) {
    __shared__ float As[16][64];
    __shared__ float Bs[16][64];
    int tid = threadIdx.x;
    int bm = blockIdx.y * 64, bn = blockIdx.x * 64;
    int tx = tid & 15, ty = tid >> 4;
    float acc[4][4] = {};
    for (int k0 = 0; k0 < K; k0 += 16) {
        {
            int r = tid >> 2, c4 = (tid & 3) * 4;
            float4 av = *(const float4*)(A + (size_t)(bm + r) * K + k0 + c4);
            As[c4 + 0][r] = av.x; As[c4 + 1][r] = av.y;
            As[c4 + 2][r] = av.z; As[c4 + 3][r] = av.w;
        }
        {
            int rb = tid >> 4, cb = (tid & 15) * 4;
            *(float4*)&Bs[rb][cb] = *(const float4*)(B + (size_t)(k0 + rb) * N + bn + cb);
        }
        __syncthreads();
        #pragma unroll
        for (int k = 0; k < 16; ++k) {
            float4 a4 = *(const float4*)&As[k][ty * 4];
            float4 b4 = *(const float4*)&Bs[k][tx * 4];
            float a[4] = {a4.x, a4.y, a4.z, a4.w};
            float b[4] = {b4.x, b4.y, b4.z, b4.w};
            #pragma unroll
            for (int i = 0; i < 4; ++i)
                #pragma unroll
                for (int j = 0; j < 4; ++j)
                    acc[i][j] += a[i] * b[j];
        }
        __syncthreads();
    }
    #pragma unroll
    for (int i = 0; i < 4; ++i) {
        int m = bm + ty * 4 + i;
        #pragma unroll
        for (int j = 0; j < 4; ++j) {
            int n = bn + tx * 4 + j;
            float vv = acc[i][j] + bias[n];
            if (epi == 1) {
                vv = gelu_f(vv);
            } else if (epi == 2) {
                int id = min(max(levels[m * 2], 0), 50);
                vv += emb[(size_t)id * N + n];
            }
            C[(size_t)m * N + n] = vv;
        }
    }
}

// ---- kernel F: per-token adapter, processed in expert-sorted order for L2 reuse ----
__global__ __launch_bounds__(256) void k_adapter(
    const float* __restrict__ h, const float* __restrict__ e_pre,
    const float* __restrict__ fg, const float* __restrict__ fbeta,
    const float* __restrict__ aW, const float* __restrict__ ab,
    const float* __restrict__ ag, const float* __restrict__ abt,
    const float* __restrict__ dw1, const float* __restrict__ db1,
    const float* __restrict__ dw2, const float* __restrict__ db2,
    const int* __restrict__ levels, const int* __restrict__ sorted,
    float* __restrict__ out) {
    int n = sorted[blockIdx.x];   // expert-sorted order -> consecutive blocks share aW[idx] in L2
    int f = threadIdx.x;
    __shared__ float red[4];
    __shared__ float hs[256];
    __shared__ float ys[256];
    __shared__ float wred[2];
    int idx = min(max(levels[n * 2], 0), 50);
    // enh = gelu(LN(e_pre; fg, fbeta)); hfull = h + 0.3*enh
    float e = e_pre[(size_t)n * DD + f];
    float s  = block_sum(e, red);
    float s2 = block_sum(e * e, red);
    float mean = s * (1.f / 256.f);
    float var = s2 * (1.f / 256.f) - mean * mean;
    float rstd = rsqrtf(var + 1e-5f);
    float enh = gelu_f((e - mean) * rstd * fg[f] + fbeta[f]);
    hs[f] = h[(size_t)n * DD + f] + 0.3f * enh;
    __syncthreads();
    // y = hfull @ aW[idx] + ab[idx]
    const float* W = aW + (size_t)idx * DD * DD;
    float acc = ab[(size_t)idx * DD + f];
    #pragma unroll 8
    for (int d = 0; d < DD; ++d) acc += hs[d] * W[(size_t)d * DD + f];
    // y = gelu(LN(y; ag[idx], abt[idx]))
    float ss  = block_sum(acc, red);
    float ss2 = block_sum(acc * acc, red);
    float m2 = ss * (1.f / 256.f);
    float v2 = ss2 * (1.f / 256.f) - m2 * m2;
    float r2 = rsqrtf(v2 + 1e-5f);
    float y = gelu_f((acc - m2) * r2 * ag[(size_t)idx * DD + f] + abt[(size_t)idx * DD + f]);
    ys[f] = y;
    __syncthreads();
    // gate: w = sigmoid(relu(y@dw1+db1)@dw2+db2)
    float part = 0.f;
    if (f < DHH) {
        float hv = db1[f];
        #pragma unroll 8
        for (int d = 0; d < DD; ++d) hv += ys[d] * dw1[(size_t)d * DHH + f];
        hv = fmaxf(hv, 0.f);
        part = hv * dw2[f];
    }
    #pragma unroll
    for (int o = 32; o > 0; o >>= 1) part += __shfl_down(part, o);
    int lane = f & 63, w = f >> 6;
    if (lane == 0 && w < 2) wred[w] = part;
    __syncthreads();
    float wp = wred[0] + wred[1] + db2[0];
    float gate = 0.8f + 0.4f / (1.f + expf(-wp));
    out[(size_t)n * DD + f] = y * gate;
}

extern "C" void kernel_launch(void* const* d_in, const int* in_sizes, int n_in,
                              void* d_out, int out_size, void* d_ws, size_t ws_size,
                              hipStream_t stream) {
    const float* tokens = (const float*)d_in[0];
    const float* ln_g = (const float*)d_in[1];
    const float* ln_b = (const float*)d_in[2];
    const float* pw1 = (const float*)d_in[3];
    const float* pb1 = (const float*)d_in[4];
    const float* pw2 = (const float*)d_in[5];
    const float* pb2 = (const float*)d_in[6];
    const float* emb = (const float*)d_in[7];
    const float* sw1 = (const float*)d_in[8];
    const float* sb1 = (const float*)d_in[9];
    const float* sw2 = (const float*)d_in[10];
    const float* sb2 = (const float*)d_in[11];
    const float* ew1 = (const float*)d_in[12];
    const float* eb1 = (const float*)d_in[13];
    const float* ew2 = (const float*)d_in[14];
    const float* eb2 = (const float*)d_in[15];
    const float* spw1 = (const float*)d_in[16];
    const float* spb1 = (const float*)d_in[17];
    const float* spw2 = (const float*)d_in[18];
    const float* spb2 = (const float*)d_in[19];
    const float* lw1 = (const float*)d_in[20];
    const float* lb1 = (const float*)d_in[21];
    const float* lw2 = (const float*)d_in[22];
    const float* lb2 = (const float*)d_in[23];
    const float* fw = (const float*)d_in[24];
    const float* fb = (const float*)d_in[25];
    const float* fg = (const float*)d_in[26];
    const float* fbeta = (const float*)d_in[27];
    const float* aW = (const float*)d_in[28];
    const float* ab = (const float*)d_in[29];
    const float* ag = (const float*)d_in[30];
    const float* abt = (const float*)d_in[31];
    const float* dw1 = (const float*)d_in[32];
    const float* db1 = (const float*)d_in[33];
    const float* dw2 = (const float*)d_in[34];
    const float* db2 = (const float*)d_in[35];
    const int* levels = (const int*)d_in[36];
    const int* ph = (const int*)d_in[37];
    const int* pw = (const int*)d_in[38];
    float* outp = (float*)d_out;

    float* ws = (float*)d_ws;
    float* x_ln  = ws;                               // 4096*768
    float* h1    = x_ln + (size_t)NTOK * IND;        // 4096*512
    float* h     = h1 + (size_t)NTOK * DD2;          // 4096*256
    float* enh_in = h + (size_t)NTOK * DD;           // 4096*256
    float* e_pre = enh_in + (size_t)NTOK * DD;       // 4096*256
    float* constf = e_pre + (size_t)NTOK * DD;       // 128
    int* sorted = (int*)(constf + 128);              // 4096
    int* off    = sorted + NTOK;                     // 52

    k_const<<<1, 64, 0, stream>>>(spw1, spb1, spw2, spb2, lw1, lb1, lw2, lb2,
                                  levels, ph, pw, constf);
    k_group<<<1, 1024, 0, stream>>>(levels, sorted, off);
    k_stats<<<NTOK, 256, 0, stream>>>(tokens, ln_g, ln_b, sw1, sb1, sw2, sb2,
                                      ew1, eb1, ew2, eb2, constf, x_ln, enh_in);
    k_gemm<<<dim3(DD2 / 64, NTOK / 64), 256, 0, stream>>>(
        x_ln, pw1, pb1, h1, NTOK, DD2, IND, 1, nullptr, nullptr);
    k_gemm<<<dim3(DD / 64, NTOK / 64), 256, 0, stream>>>(
        h1, pw2, pb2, h, NTOK, DD, DD2, 2, levels, emb);
    k_gemm<<<dim3(DD / 64, NTOK / 64), 256, 0, stream>>>(
        enh_in, fw, fb, e_pre, NTOK, DD, DD, 0, nullptr, nullptr);
    k_adapter<<<NTOK, 256, 0, stream>>>(h, e_pre, fg, fbeta, aW, ab, ag, abt,
                                        dw1, db1, dw2, db2, levels, sorted, outp);
}

// Round 4
// 112.916 us; speedup vs baseline: 6.9729x; 1.7467x over previous
//
#include <hip/hip_runtime.h>
#include <math.h>

#define NTOK 4096
#define IND 768
#define DD 256
#define DD2 512
#define DHH 128
#define NEXP 51
#define NTILE_MAX 1088

typedef __attribute__((ext_vector_type(4))) float f32x4;
typedef __attribute__((ext_vector_type(8))) short short8;

__device__ __forceinline__ float gelu_f(float x) {
    return 0.5f * x * (1.0f + erff(x * 0.70710678118654752440f));
}
// fp32 -> bf16 round-to-nearest-even
__device__ __forceinline__ ushort f2bf(float x) {
    unsigned u = __float_as_uint(x);
    return (ushort)((u + 0x7fffu + ((u >> 16) & 1u)) >> 16);
}

// block-wide sum for 256 threads (4 waves)
__device__ __forceinline__ float block_sum(float v, float* lds) {
    #pragma unroll
    for (int o = 32; o > 0; o >>= 1) v += __shfl_down(v, o);
    int lane = threadIdx.x & 63, w = threadIdx.x >> 6;
    if (lane == 0) lds[w] = v;
    __syncthreads();
    float r = lds[0] + lds[1] + lds[2] + lds[3];
    __syncthreads();
    return r;
}

// ---- kernel: token-independent spatial_feat / level_feat ----
__global__ __launch_bounds__(64) void k_const(
    const float* __restrict__ spw1, const float* __restrict__ spb1,
    const float* __restrict__ spw2, const float* __restrict__ spb2,
    const float* __restrict__ lw1, const float* __restrict__ lb1,
    const float* __restrict__ lw2, const float* __restrict__ lb2,
    const int* __restrict__ levels, const int* __restrict__ ph, const int* __restrict__ pw,
    float* __restrict__ constf) {
    __shared__ float hs[64], hl[64];
    int t = threadIdx.x;
    float p0 = (float)ph[0], p1 = (float)pw[0];
    float lvl = (float)levels[0];
    hs[t] = fmaxf(0.f, p0 * spw1[t] + p1 * spw1[64 + t] + spb1[t]);
    hl[t] = fmaxf(0.f, lvl * lw1[t] + lb1[t]);
    __syncthreads();
    float a = spb2[t], b = lb2[t];
    for (int j = 0; j < 64; ++j) {
        a += hs[j] * spw2[j * 64 + t];
        b += hl[j] * lw2[j * 64 + t];
    }
    constf[t] = a;
    constf[64 + t] = b;
}

// ---- weight transpose + bf16 convert: pw1T[512][768], pw2T[256][512], fwT[256][256] ----
__global__ __launch_bounds__(256) void k_wconv(
    const float* __restrict__ pw1, const float* __restrict__ pw2,
    const float* __restrict__ fw,
    ushort* __restrict__ pw1T, ushort* __restrict__ pw2T, ushort* __restrict__ fwT) {
    int id = blockIdx.x * 256 + threadIdx.x;
    const int S1 = IND * DD2, S2 = DD * DD2, S3 = DD * DD;
    if (id < S1) {
        int n = id / IND, k = id - n * IND;
        pw1T[id] = f2bf(pw1[(size_t)k * DD2 + n]);
    } else if (id < S1 + S2) {
        int j = id - S1;
        int n = j / DD2, k = j - n * DD2;
        pw2T[j] = f2bf(pw2[(size_t)k * DD + n]);
    } else if (id < S1 + S2 + S3) {
        int j = id - S1 - S2;
        int n = j / DD, k = j - n * DD;
        fwT[j] = f2bf(fw[(size_t)k * DD + n]);
    }
}

// ---- expert grouping: histogram + prefix + scatter + 4-token tile build ----
__global__ __launch_bounds__(1024) void k_group(
    const int* __restrict__ levels, int* __restrict__ sorted,
    int* __restrict__ tpos, int* __restrict__ tcnt, int* __restrict__ texp,
    int* __restrict__ meta) {
    __shared__ int cnt[NEXP], cur[NEXP], offS[NEXP + 1], tileoff[NEXP + 1];
    __shared__ int expS[NTOK];
    int t = threadIdx.x;
    if (t < NEXP) cnt[t] = 0;
    __syncthreads();
    int myidx[4];
    #pragma unroll
    for (int i = 0; i < 4; ++i) {
        int n = t + i * 1024;
        int id = min(max(levels[n * 2], 0), NEXP - 1);
        myidx[i] = id;
        atomicAdd(&cnt[id], 1);
    }
    __syncthreads();
    if (t == 0) {
        int a = 0, ta = 0;
        for (int e = 0; e < NEXP; ++e) {
            offS[e] = a; cur[e] = a; tileoff[e] = ta;
            ta += (cnt[e] + 3) >> 2;
            a += cnt[e];
        }
        offS[NEXP] = a; tileoff[NEXP] = ta;
        meta[0] = ta;
    }
    __syncthreads();
    #pragma unroll
    for (int i = 0; i < 4; ++i) {
        int n = t + i * 1024;
        int p = atomicAdd(&cur[myidx[i]], 1);
        sorted[p] = n;
        expS[p] = myidx[i];
    }
    __syncthreads();
    #pragma unroll
    for (int i = 0; i < 4; ++i) {
        int p = t + i * 1024;
        int e = expS[p];
        int rel = p - offS[e];
        if ((rel & 3) == 0) {
            int ti = tileoff[e] + (rel >> 2);
            tpos[ti] = p;
            tcnt[ti] = min(4, offS[e + 1] - p);
            texp[ti] = e;
        }
    }
}

// ---- per-token LN, stats, edge, stats/edge MLPs, enh assembly (bf16 outputs) ----
__global__ __launch_bounds__(256) void k_stats(
    const float* __restrict__ tokens,
    const float* __restrict__ ln_g, const float* __restrict__ ln_b,
    const float* __restrict__ sw1, const float* __restrict__ sb1,
    const float* __restrict__ sw2, const float* __restrict__ sb2,
    const float* __restrict__ ew1, const float* __restrict__ eb1,
    const float* __restrict__ ew2, const float* __restrict__ eb2,
    const float* __restrict__ constf,
    ushort* __restrict__ x_ln, ushort* __restrict__ enh) {
    int n = blockIdx.x, t = threadIdx.x;
    const float* x = tokens + (size_t)n * IND;
    __shared__ float red[4];
    float v[3];
    float s = 0.f, s2 = 0.f, es = 0.f;
    #pragma unroll
    for (int i = 0; i < 3; ++i) {
        int e = t + i * 256;
        float xv = x[e];
        v[i] = xv;
        s += xv; s2 += xv * xv;
        if (e > 0) es += fabsf(xv - x[e - 1]);
    }
    s  = block_sum(s, red);
    s2 = block_sum(s2, red);
    es = block_sum(es, red);
    float mean = s * (1.f / 768.f);
    float var_u = (s2 - 768.f * mean * mean) * (1.f / 767.f);
    float rstd = rsqrtf(s2 * (1.f / 768.f) - mean * mean + 1e-5f);
    float edge = es * (1.f / 767.f);
    #pragma unroll
    for (int i = 0; i < 3; ++i) {
        int e = t + i * 256;
        x_ln[(size_t)n * IND + e] = f2bf((v[i] - mean) * rstd * ln_g[e] + ln_b[e]);
    }
    __shared__ float hid[128];
    if (t < 64) {
        hid[t] = fmaxf(0.f, var_u * sw1[t] + mean * sw1[64 + t] + sb1[t]);
    } else if (t < 128) {
        int j = t - 64;
        hid[64 + j] = fmaxf(0.f, edge * ew1[j] + eb1[j]);
    }
    __syncthreads();
    ushort* er = enh + (size_t)n * DD;
    if (t < 64) {
        float a = sb2[t];
        for (int j = 0; j < 64; ++j) a += hid[j] * sw2[j * 64 + t];
        er[t] = f2bf(a);
    } else if (t < 128) {
        int k = t - 64;
        float a = eb2[k];
        for (int j = 0; j < 64; ++j) a += hid[64 + j] * ew2[j * 64 + k];
        er[64 + k] = f2bf(a);
    } else {
        er[t] = f2bf(constf[t - 128]);
    }
}

// ---- bf16 MFMA GEMM: C[M,N] = A[M,K] @ BT[N,K]^T, tile 64 x TN, BK=64 ----
// epi: 1 = gelu(v+bias) -> bf16 Cb ; 2 = v+bias+emb[idx] -> f32 Cf ; 0 = v+bias -> f32 Cf
template<int TN>
__global__ __launch_bounds__(256) void k_mgemm(
    const ushort* __restrict__ A, const ushort* __restrict__ BT,
    int M, int N, int K, int epi,
    const float* __restrict__ bias,
    const int* __restrict__ levels, const float* __restrict__ emb,
    float* __restrict__ Cf, ushort* __restrict__ Cb) {
    constexpr int NF = TN / 16;
    __shared__ ushort Al[64][72];
    __shared__ ushort Bl[TN][72];
    int tid = threadIdx.x;
    int w = tid >> 6, lane = tid & 63;
    int g = lane >> 4, mr = lane & 15;
    int bm = blockIdx.y * 64, bn = blockIdx.x * TN;
    f32x4 acc[NF];
    #pragma unroll
    for (int f = 0; f < NF; ++f) acc[f] = (f32x4){0.f, 0.f, 0.f, 0.f};
    for (int k0 = 0; k0 < K; k0 += 64) {
        #pragma unroll
        for (int i = 0; i < 2; ++i) {
            int c = tid + 256 * i;
            int r = c >> 3, c8 = (c & 7) * 8;
            *(short8*)&Al[r][c8] = *(const short8*)(A + (size_t)(bm + r) * K + k0 + c8);
        }
        #pragma unroll
        for (int i = 0; i < TN / 32; ++i) {
            int c = tid + 256 * i;
            int r = c >> 3, c8 = (c & 7) * 8;
            *(short8*)&Bl[r][c8] = *(const short8*)(BT + (size_t)(bn + r) * K + k0 + c8);
        }
        __syncthreads();
        #pragma unroll
        for (int kk = 0; kk < 64; kk += 32) {
            short8 av = *(const short8*)&Al[16 * w + mr][kk + g * 8];
            #pragma unroll
            for (int f = 0; f < NF; ++f) {
                short8 bv = *(const short8*)&Bl[16 * f + mr][kk + g * 8];
                acc[f] = __builtin_amdgcn_mfma_f32_16x16x32_bf16(av, bv, acc[f], 0, 0, 0);
            }
        }
        __syncthreads();
    }
    #pragma unroll
    for (int f = 0; f < NF; ++f) {
        int col = bn + 16 * f + mr;
        #pragma unroll
        for (int r = 0; r < 4; ++r) {
            int row = bm + 16 * w + 4 * g + r;
            float v = acc[f][r];
            if (epi == 1) {
                v = gelu_f(v + bias[col]);
                Cb[(size_t)row * N + col] = f2bf(v);
            } else if (epi == 2) {
                int id = min(max(levels[row * 2], 0), NEXP - 1);
                Cf[(size_t)row * N + col] = v + bias[col] + emb[(size_t)id * N + col];
            } else {
                Cf[(size_t)row * N + col] = v + bias[col];
            }
        }
    }
}

// ---- hfull = h + 0.3*gelu(LN(e_pre; fg,fbeta)) ; one wave per token ----
__global__ __launch_bounds__(256) void k_hfull(
    const float* __restrict__ h, const float* __restrict__ e_pre,
    const float* __restrict__ fg, const float* __restrict__ fbeta,
    float* __restrict__ hfull) {
    int tok = blockIdx.x * 4 + (threadIdx.x >> 6);
    int lane = threadIdx.x & 63;
    float4 e4 = *(const float4*)(e_pre + (size_t)tok * DD + lane * 4);
    float s = e4.x + e4.y + e4.z + e4.w;
    float s2 = e4.x * e4.x + e4.y * e4.y + e4.z * e4.z + e4.w * e4.w;
    #pragma unroll
    for (int o = 1; o < 64; o <<= 1) { s += __shfl_xor(s, o); s2 += __shfl_xor(s2, o); }
    float m = s * (1.f / 256.f);
    float rs = rsqrtf(s2 * (1.f / 256.f) - m * m + 1e-5f);
    float4 h4 = *(const float4*)(h + (size_t)tok * DD + lane * 4);
    float4 g4 = *(const float4*)(fg + lane * 4);
    float4 b4 = *(const float4*)(fbeta + lane * 4);
    float4 o4;
    o4.x = h4.x + 0.3f * gelu_f((e4.x - m) * rs * g4.x + b4.x);
    o4.y = h4.y + 0.3f * gelu_f((e4.y - m) * rs * g4.y + b4.y);
    o4.z = h4.z + 0.3f * gelu_f((e4.z - m) * rs * g4.z + b4.z);
    o4.w = h4.w + 0.3f * gelu_f((e4.w - m) * rs * g4.w + b4.w);
    *(float4*)(hfull + (size_t)tok * DD + lane * 4) = o4;
}

// ---- 4-token expert adapter: y = hfull@aW[e]+ab, LN+gelu, gate, scatter ----
__global__ __launch_bounds__(256) void k_adapter4(
    const float* __restrict__ hfull,
    const float* __restrict__ aW, const float* __restrict__ ab,
    const float* __restrict__ ag, const float* __restrict__ abt,
    const float* __restrict__ dw1, const float* __restrict__ db1,
    const float* __restrict__ dw2, const float* __restrict__ db2,
    const int* __restrict__ sorted, const int* __restrict__ tpos,
    const int* __restrict__ tcnt, const int* __restrict__ texp,
    const int* __restrict__ meta,
    float* __restrict__ out) {
    __shared__ float redS[4][8];
    __shared__ float yt[DD][4];
    __shared__ float gred[2][4];
    int b = blockIdx.x;
    if (b >= meta[0]) return;
    int f = threadIdx.x;
    int wv = f >> 6, lane = f & 63;
    int e = texp[b], base = tpos[b], nv = tcnt[b];
    int tok[4];
    #pragma unroll
    for (int r = 0; r < 4; ++r) tok[r] = sorted[base + min(r, nv - 1)];
    const float* hf0 = hfull + (size_t)__builtin_amdgcn_readfirstlane(tok[0]) * DD;
    const float* hf1 = hfull + (size_t)__builtin_amdgcn_readfirstlane(tok[1]) * DD;
    const float* hf2 = hfull + (size_t)__builtin_amdgcn_readfirstlane(tok[2]) * DD;
    const float* hf3 = hfull + (size_t)__builtin_amdgcn_readfirstlane(tok[3]) * DD;
    const float* W = aW + (size_t)e * DD * DD;
    float acc[4] = {0.f, 0.f, 0.f, 0.f};
    #pragma unroll 2
    for (int d0 = 0; d0 < DD; d0 += 8) {
        #pragma unroll
        for (int j = 0; j < 8; ++j) {
            float wj = W[(size_t)(d0 + j) * DD + f];
            acc[0] += hf0[d0 + j] * wj;
            acc[1] += hf1[d0 + j] * wj;
            acc[2] += hf2[d0 + j] * wj;
            acc[3] += hf3[d0 + j] * wj;
        }
    }
    float sv[8];
    float abf = ab[(size_t)e * DD + f];
    #pragma unroll
    for (int r = 0; r < 4; ++r) {
        acc[r] += abf;
        sv[r] = acc[r]; sv[4 + r] = acc[r] * acc[r];
    }
    #pragma unroll
    for (int o = 1; o < 64; o <<= 1) {
        #pragma unroll
        for (int j = 0; j < 8; ++j) sv[j] += __shfl_xor(sv[j], o);
    }
    if (lane == 0) {
        #pragma unroll
        for (int j = 0; j < 8; ++j) redS[wv][j] = sv[j];
    }
    __syncthreads();
    float y[4];
    float agf = ag[(size_t)e * DD + f], abtf = abt[(size_t)e * DD + f];
    #pragma unroll
    for (int r = 0; r < 4; ++r) {
        float s = redS[0][r] + redS[1][r] + redS[2][r] + redS[3][r];
        float s2 = redS[0][4 + r] + redS[1][4 + r] + redS[2][4 + r] + redS[3][4 + r];
        float m = s * (1.f / 256.f);
        float rs = rsqrtf(s2 * (1.f / 256.f) - m * m + 1e-5f);
        y[r] = gelu_f((acc[r] - m) * rs * agf + abtf);
    }
    *(float4*)&yt[f][0] = (float4){y[0], y[1], y[2], y[3]};
    __syncthreads();
    if (f < DHH) {
        float d1 = db1[f];
        float hv[4] = {d1, d1, d1, d1};
        #pragma unroll 4
        for (int d = 0; d < DD; ++d) {
            float wv_ = dw1[(size_t)d * DHH + f];
            float4 yv = *(const float4*)&yt[d][0];
            hv[0] += yv.x * wv_; hv[1] += yv.y * wv_;
            hv[2] += yv.z * wv_; hv[3] += yv.w * wv_;
        }
        float d2 = dw2[f];
        float p[4];
        #pragma unroll
        for (int r = 0; r < 4; ++r) p[r] = fmaxf(hv[r], 0.f) * d2;
        #pragma unroll
        for (int o = 1; o < 64; o <<= 1) {
            #pragma unroll
            for (int r = 0; r < 4; ++r) p[r] += __shfl_xor(p[r], o);
        }
        if (lane == 0) {
            #pragma unroll
            for (int r = 0; r < 4; ++r) gred[wv][r] = p[r];
        }
    }
    __syncthreads();
    float dbv = db2[0];
    #pragma unroll
    for (int r = 0; r < 4; ++r) {
        if (r < nv) {
            float gw = gred[0][r] + gred[1][r] + dbv;
            float gate = 0.8f + 0.4f / (1.f + expf(-gw));
            out[(size_t)tok[r] * DD + f] = y[r] * gate;
        }
    }
}

extern "C" void kernel_launch(void* const* d_in, const int* in_sizes, int n_in,
                              void* d_out, int out_size, void* d_ws, size_t ws_size,
                              hipStream_t stream) {
    const float* tokens = (const float*)d_in[0];
    const float* ln_g = (const float*)d_in[1];
    const float* ln_b = (const float*)d_in[2];
    const float* pw1 = (const float*)d_in[3];
    const float* pb1 = (const float*)d_in[4];
    const float* pw2 = (const float*)d_in[5];
    const float* pb2 = (const float*)d_in[6];
    const float* emb = (const float*)d_in[7];
    const float* sw1 = (const float*)d_in[8];
    const float* sb1 = (const float*)d_in[9];
    const float* sw2 = (const float*)d_in[10];
    const float* sb2 = (const float*)d_in[11];
    const float* ew1 = (const float*)d_in[12];
    const float* eb1 = (const float*)d_in[13];
    const float* ew2 = (const float*)d_in[14];
    const float* eb2 = (const float*)d_in[15];
    const float* spw1 = (const float*)d_in[16];
    const float* spb1 = (const float*)d_in[17];
    const float* spw2 = (const float*)d_in[18];
    const float* spb2 = (const float*)d_in[19];
    const float* lw1 = (const float*)d_in[20];
    const float* lb1 = (const float*)d_in[21];
    const float* lw2 = (const float*)d_in[22];
    const float* lb2 = (const float*)d_in[23];
    const float* fw = (const float*)d_in[24];
    const float* fb = (const float*)d_in[25];
    const float* fg = (const float*)d_in[26];
    const float* fbeta = (const float*)d_in[27];
    const float* aW = (const float*)d_in[28];
    const float* ab = (const float*)d_in[29];
    const float* ag = (const float*)d_in[30];
    const float* abt = (const float*)d_in[31];
    const float* dw1 = (const float*)d_in[32];
    const float* db1 = (const float*)d_in[33];
    const float* dw2 = (const float*)d_in[34];
    const float* db2 = (const float*)d_in[35];
    const int* levels = (const int*)d_in[36];
    const int* ph = (const int*)d_in[37];
    const int* pw = (const int*)d_in[38];
    float* outp = (float*)d_out;

    char* wsb = (char*)d_ws;
    ushort* x_ln  = (ushort*)wsb;                          wsb += (size_t)NTOK * IND * 2;
    ushort* h1    = (ushort*)wsb;                          wsb += (size_t)NTOK * DD2 * 2;
    ushort* enh   = (ushort*)wsb;                          wsb += (size_t)NTOK * DD * 2;
    float*  h     = (float*)wsb;                           wsb += (size_t)NTOK * DD * 4;
    float*  e_pre = (float*)wsb;                           wsb += (size_t)NTOK * DD * 4;
    float*  hfull = (float*)wsb;                           wsb += (size_t)NTOK * DD * 4;
    ushort* pw1T  = (ushort*)wsb;                          wsb += (size_t)DD2 * IND * 2;
    ushort* pw2T  = (ushort*)wsb;                          wsb += (size_t)DD * DD2 * 2;
    ushort* fwT   = (ushort*)wsb;                          wsb += (size_t)DD * DD * 2;
    float*  constf = (float*)wsb;                          wsb += 512;
    int*    sorted = (int*)wsb;                            wsb += NTOK * 4;
    int*    tpos   = (int*)wsb;                            wsb += NTILE_MAX * 4;
    int*    tcnt   = (int*)wsb;                            wsb += NTILE_MAX * 4;
    int*    texp   = (int*)wsb;                            wsb += NTILE_MAX * 4;
    int*    meta   = (int*)wsb;                            wsb += 64;

    k_wconv<<<2304, 256, 0, stream>>>(pw1, pw2, fw, pw1T, pw2T, fwT);
    k_group<<<1, 1024, 0, stream>>>(levels, sorted, tpos, tcnt, texp, meta);
    k_const<<<1, 64, 0, stream>>>(spw1, spb1, spw2, spb2, lw1, lb1, lw2, lb2,
                                  levels, ph, pw, constf);
    k_stats<<<NTOK, 256, 0, stream>>>(tokens, ln_g, ln_b, sw1, sb1, sw2, sb2,
                                      ew1, eb1, ew2, eb2, constf, x_ln, enh);
    // h1 = gelu(x_ln @ pw1 + pb1)   [4096,768]x[768,512] -> bf16
    k_mgemm<64><<<dim3(DD2 / 64, NTOK / 64), 256, 0, stream>>>(
        x_ln, pw1T, NTOK, DD2, IND, 1, pb1, nullptr, nullptr, nullptr, h1);
    // h = h1 @ pw2 + pb2 + emb[idx]  [4096,512]x[512,256] -> f32
    k_mgemm<32><<<dim3(DD / 32, NTOK / 64), 256, 0, stream>>>(
        h1, pw2T, NTOK, DD, DD2, 2, pb2, levels, emb, h, nullptr);
    // e_pre = enh @ fw + fb          [4096,256]x[256,256] -> f32
    k_mgemm<32><<<dim3(DD / 32, NTOK / 64), 256, 0, stream>>>(
        enh, fwT, NTOK, DD, DD, 0, fb, nullptr, nullptr, e_pre, nullptr);
    k_hfull<<<NTOK / 4, 256, 0, stream>>>(h, e_pre, fg, fbeta, hfull);
    k_adapter4<<<NTILE_MAX, 256, 0, stream>>>(hfull, aW, ab, ag, abt,
                                              dw1, db1, dw2, db2,
                                              sorted, tpos, tcnt, texp, meta, outp);
}

// Round 5
// 109.935 us; speedup vs baseline: 7.1620x; 1.0271x over previous
//
#include <hip/hip_runtime.h>
#include <math.h>

#define NTOK 4096
#define IND 768
#define DD 256
#define DD2 512
#define DHH 128
#define NEXP 51
#define TM 32
#define NTILE_MAX 179   // floor(4096/32) + 51

typedef __attribute__((ext_vector_type(4))) float f32x4;
typedef __attribute__((ext_vector_type(8))) short short8;

__device__ __forceinline__ float gelu_f(float x) {
    return 0.5f * x * (1.0f + erff(x * 0.70710678118654752440f));
}
__device__ __forceinline__ ushort f2bf(float x) {
    unsigned u = __float_as_uint(x);
    return (ushort)((u + 0x7fffu + ((u >> 16) & 1u)) >> 16);
}
__device__ __forceinline__ float bf2f(ushort u) {
    return __uint_as_float((unsigned)u << 16);
}

// block-wide sum for 256 threads (4 waves)
__device__ __forceinline__ float block_sum(float v, float* lds) {
    #pragma unroll
    for (int o = 32; o > 0; o >>= 1) v += __shfl_down(v, o);
    int lane = threadIdx.x & 63, w = threadIdx.x >> 6;
    if (lane == 0) lds[w] = v;
    __syncthreads();
    float r = lds[0] + lds[1] + lds[2] + lds[3];
    __syncthreads();
    return r;
}

// ---- token-independent spatial_feat / level_feat ----
__global__ __launch_bounds__(64) void k_const(
    const float* __restrict__ spw1, const float* __restrict__ spb1,
    const float* __restrict__ spw2, const float* __restrict__ spb2,
    const float* __restrict__ lw1, const float* __restrict__ lb1,
    const float* __restrict__ lw2, const float* __restrict__ lb2,
    const int* __restrict__ levels, const int* __restrict__ ph, const int* __restrict__ pw,
    float* __restrict__ constf) {
    __shared__ float hs[64], hl[64];
    int t = threadIdx.x;
    float p0 = (float)ph[0], p1 = (float)pw[0];
    float lvl = (float)levels[0];
    hs[t] = fmaxf(0.f, p0 * spw1[t] + p1 * spw1[64 + t] + spb1[t]);
    hl[t] = fmaxf(0.f, lvl * lw1[t] + lb1[t]);
    __syncthreads();
    float a = spb2[t], b = lb2[t];
    for (int j = 0; j < 64; ++j) {
        a += hs[j] * spw2[j * 64 + t];
        b += hl[j] * lw2[j * 64 + t];
    }
    constf[t] = a;
    constf[64 + t] = b;
}

// ---- weight convert/transpose:
// pw1T[512][768], pw2T[256][512], fwT[256][256], aWT[E][256 n][256 k], dw1T[128][256] (all bf16)
__global__ __launch_bounds__(256) void k_wconv(
    const float* __restrict__ pw1, const float* __restrict__ pw2,
    const float* __restrict__ fw, const float* __restrict__ aW,
    const float* __restrict__ dw1,
    ushort* __restrict__ pw1T, ushort* __restrict__ pw2T, ushort* __restrict__ fwT,
    ushort* __restrict__ aWT, ushort* __restrict__ dw1T) {
    int id = blockIdx.x * 256 + threadIdx.x;
    const int S1 = IND * DD2, S2 = DD * DD2, S3 = DD * DD;
    const int S4 = NEXP * DD * DD, S5 = DD * DHH;
    if (id < S1) {
        int n = id / IND, k = id - n * IND;
        pw1T[id] = f2bf(pw1[(size_t)k * DD2 + n]);
    } else if (id < S1 + S2) {
        int j = id - S1;
        int n = j / DD2, k = j - n * DD2;
        pw2T[j] = f2bf(pw2[(size_t)k * DD + n]);
    } else if (id < S1 + S2 + S3) {
        int j = id - S1 - S2;
        int n = j / DD, k = j - n * DD;
        fwT[j] = f2bf(fw[(size_t)k * DD + n]);
    } else if (id < S1 + S2 + S3 + S4) {
        int j = id - S1 - S2 - S3;
        int e = j / (DD * DD), rem = j - e * DD * DD;
        int n = rem / DD, k = rem - n * DD;
        aWT[j] = f2bf(aW[(size_t)e * DD * DD + (size_t)k * DD + n]);
    } else if (id < S1 + S2 + S3 + S4 + S5) {
        int j = id - S1 - S2 - S3 - S4;
        int n = j / DD, k = j - n * DD;
        dw1T[j] = f2bf(dw1[(size_t)k * DHH + n]);
    }
}

// ---- expert grouping: histogram + prefix + scatter + 32-token tile build ----
__global__ __launch_bounds__(1024) void k_group(
    const int* __restrict__ levels, int* __restrict__ sorted,
    int* __restrict__ tpos, int* __restrict__ tcnt, int* __restrict__ texp,
    int* __restrict__ meta) {
    __shared__ int cnt[NEXP], cur[NEXP], offS[NEXP + 1], tileoff[NEXP + 1];
    __shared__ int expS[NTOK];
    int t = threadIdx.x;
    if (t < NEXP) cnt[t] = 0;
    __syncthreads();
    int myidx[4];
    #pragma unroll
    for (int i = 0; i < 4; ++i) {
        int n = t + i * 1024;
        int id = min(max(levels[n * 2], 0), NEXP - 1);
        myidx[i] = id;
        atomicAdd(&cnt[id], 1);
    }
    __syncthreads();
    if (t == 0) {
        int a = 0, ta = 0;
        for (int e = 0; e < NEXP; ++e) {
            offS[e] = a; cur[e] = a; tileoff[e] = ta;
            ta += (cnt[e] + TM - 1) / TM;
            a += cnt[e];
        }
        offS[NEXP] = a; tileoff[NEXP] = ta;
        meta[0] = ta;
    }
    __syncthreads();
    #pragma unroll
    for (int i = 0; i < 4; ++i) {
        int n = t + i * 1024;
        int p = atomicAdd(&cur[myidx[i]], 1);
        sorted[p] = n;
        expS[p] = myidx[i];
    }
    __syncthreads();
    #pragma unroll
    for (int i = 0; i < 4; ++i) {
        int p = t + i * 1024;
        int e = expS[p];
        int rel = p - offS[e];
        if ((rel & (TM - 1)) == 0) {
            int ti = tileoff[e] + (rel / TM);
            tpos[ti] = p;
            tcnt[ti] = min(TM, offS[e + 1] - p);
            texp[ti] = e;
        }
    }
}

// ---- per-token LN, stats, edge, stats/edge MLPs, enh assembly (bf16 outputs) ----
__global__ __launch_bounds__(256) void k_stats(
    const float* __restrict__ tokens,
    const float* __restrict__ ln_g, const float* __restrict__ ln_b,
    const float* __restrict__ sw1, const float* __restrict__ sb1,
    const float* __restrict__ sw2, const float* __restrict__ sb2,
    const float* __restrict__ ew1, const float* __restrict__ eb1,
    const float* __restrict__ ew2, const float* __restrict__ eb2,
    const float* __restrict__ constf,
    ushort* __restrict__ x_ln, ushort* __restrict__ enh) {
    int n = blockIdx.x, t = threadIdx.x;
    const float* x = tokens + (size_t)n * IND;
    __shared__ float red[4];
    float v[3];
    float s = 0.f, s2 = 0.f, es = 0.f;
    #pragma unroll
    for (int i = 0; i < 3; ++i) {
        int e = t + i * 256;
        float xv = x[e];
        v[i] = xv;
        s += xv; s2 += xv * xv;
        if (e > 0) es += fabsf(xv - x[e - 1]);
    }
    s  = block_sum(s, red);
    s2 = block_sum(s2, red);
    es = block_sum(es, red);
    float mean = s * (1.f / 768.f);
    float var_u = (s2 - 768.f * mean * mean) * (1.f / 767.f);
    float rstd = rsqrtf(s2 * (1.f / 768.f) - mean * mean + 1e-5f);
    float edge = es * (1.f / 767.f);
    #pragma unroll
    for (int i = 0; i < 3; ++i) {
        int e = t + i * 256;
        x_ln[(size_t)n * IND + e] = f2bf((v[i] - mean) * rstd * ln_g[e] + ln_b[e]);
    }
    __shared__ float hid[128];
    if (t < 64) {
        hid[t] = fmaxf(0.f, var_u * sw1[t] + mean * sw1[64 + t] + sb1[t]);
    } else if (t < 128) {
        int j = t - 64;
        hid[64 + j] = fmaxf(0.f, edge * ew1[j] + eb1[j]);
    }
    __syncthreads();
    ushort* er = enh + (size_t)n * DD;
    if (t < 64) {
        float a = sb2[t];
        for (int j = 0; j < 64; ++j) a += hid[j] * sw2[j * 64 + t];
        er[t] = f2bf(a);
    } else if (t < 128) {
        int k = t - 64;
        float a = eb2[k];
        for (int j = 0; j < 64; ++j) a += hid[64 + j] * ew2[j * 64 + k];
        er[64 + k] = f2bf(a);
    } else {
        er[t] = f2bf(constf[t - 128]);
    }
}

// ---- bf16 MFMA GEMM: C[M,N] = A[M,K] @ BT[N,K]^T, tile 64 x TN, BK=64 ----
// epi: 0 = v+bias -> f32; 1 = gelu(v+bias) -> bf16; 2 = v+bias+emb[idx] -> f32; 3 = relu(v+bias) -> bf16
template<int TN>
__global__ __launch_bounds__(256) void k_mgemm(
    const ushort* __restrict__ A, const ushort* __restrict__ BT,
    int M, int N, int K, int epi,
    const float* __restrict__ bias,
    const int* __restrict__ levels, const float* __restrict__ emb,
    float* __restrict__ Cf, ushort* __restrict__ Cb) {
    constexpr int NF = TN / 16;
    __shared__ ushort Al[64][72];
    __shared__ ushort Bl[TN][72];
    int tid = threadIdx.x;
    int w = tid >> 6, lane = tid & 63;
    int g = lane >> 4, mr = lane & 15;
    int bm = blockIdx.y * 64, bn = blockIdx.x * TN;
    f32x4 acc[NF];
    #pragma unroll
    for (int f = 0; f < NF; ++f) acc[f] = (f32x4){0.f, 0.f, 0.f, 0.f};
    for (int k0 = 0; k0 < K; k0 += 64) {
        #pragma unroll
        for (int i = 0; i < 2; ++i) {
            int c = tid + 256 * i;
            int r = c >> 3, c8 = (c & 7) * 8;
            *(short8*)&Al[r][c8] = *(const short8*)(A + (size_t)(bm + r) * K + k0 + c8);
        }
        #pragma unroll
        for (int i = 0; i < TN / 32; ++i) {
            int c = tid + 256 * i;
            int r = c >> 3, c8 = (c & 7) * 8;
            *(short8*)&Bl[r][c8] = *(const short8*)(BT + (size_t)(bn + r) * K + k0 + c8);
        }
        __syncthreads();
        #pragma unroll
        for (int kk = 0; kk < 64; kk += 32) {
            short8 av = *(const short8*)&Al[16 * w + mr][kk + g * 8];
            #pragma unroll
            for (int f = 0; f < NF; ++f) {
                short8 bv = *(const short8*)&Bl[16 * f + mr][kk + g * 8];
                acc[f] = __builtin_amdgcn_mfma_f32_16x16x32_bf16(av, bv, acc[f], 0, 0, 0);
            }
        }
        __syncthreads();
    }
    #pragma unroll
    for (int f = 0; f < NF; ++f) {
        int col = bn + 16 * f + mr;
        #pragma unroll
        for (int r = 0; r < 4; ++r) {
            int row = bm + 16 * w + 4 * g + r;
            float v = acc[f][r];
            if (epi == 1) {
                Cb[(size_t)row * N + col] = f2bf(gelu_f(v + bias[col]));
            } else if (epi == 3) {
                Cb[(size_t)row * N + col] = f2bf(fmaxf(v + bias[col], 0.f));
            } else if (epi == 2) {
                int id = min(max(levels[row * 2], 0), NEXP - 1);
                Cf[(size_t)row * N + col] = v + bias[col] + emb[(size_t)id * N + col];
            } else {
                Cf[(size_t)row * N + col] = v + bias[col];
            }
        }
    }
}

// ---- hfull(bf16) = h + 0.3*gelu(LN(e_pre; fg,fbeta)) ; one wave per token ----
__global__ __launch_bounds__(256) void k_hfull(
    const float* __restrict__ h, const float* __restrict__ e_pre,
    const float* __restrict__ fg, const float* __restrict__ fbeta,
    ushort* __restrict__ hfullb) {
    int tok = blockIdx.x * 4 + (threadIdx.x >> 6);
    int lane = threadIdx.x & 63;
    float4 e4 = *(const float4*)(e_pre + (size_t)tok * DD + lane * 4);
    float s = e4.x + e4.y + e4.z + e4.w;
    float s2 = e4.x * e4.x + e4.y * e4.y + e4.z * e4.z + e4.w * e4.w;
    #pragma unroll
    for (int o = 1; o < 64; o <<= 1) { s += __shfl_xor(s, o); s2 += __shfl_xor(s2, o); }
    float m = s * (1.f / 256.f);
    float rs = rsqrtf(s2 * (1.f / 256.f) - m * m + 1e-5f);
    float4 h4 = *(const float4*)(h + (size_t)tok * DD + lane * 4);
    float4 g4 = *(const float4*)(fg + lane * 4);
    float4 b4 = *(const float4*)(fbeta + lane * 4);
    ushort4 o4;
    o4.x = f2bf(h4.x + 0.3f * gelu_f((e4.x - m) * rs * g4.x + b4.x));
    o4.y = f2bf(h4.y + 0.3f * gelu_f((e4.y - m) * rs * g4.y + b4.y));
    o4.z = f2bf(h4.z + 0.3f * gelu_f((e4.z - m) * rs * g4.z + b4.z));
    o4.w = f2bf(h4.w + 0.3f * gelu_f((e4.w - m) * rs * g4.w + b4.w));
    *(ushort4*)(hfullb + (size_t)tok * DD + lane * 4) = o4;
}

// ---- grouped expert MFMA GEMM: y_pre[tok, :] = hfull[tok,:] @ aW[e] + ab[e] ----
// grid: (4 col-slices of 64, NTILE_MAX); block 256 thr; tile TM=32 tokens
__global__ __launch_bounds__(256) void k_egemm(
    const ushort* __restrict__ hfullb, const ushort* __restrict__ aWT,
    const float* __restrict__ ab,
    const int* __restrict__ sorted, const int* __restrict__ tpos,
    const int* __restrict__ tcnt, const int* __restrict__ texp,
    const int* __restrict__ meta,
    float* __restrict__ yws) {
    int by = blockIdx.y;
    if (by >= meta[0]) return;
    __shared__ ushort Al[TM][72];
    __shared__ ushort Bl[64][72];
    __shared__ int tokS[TM];
    int tid = threadIdx.x;
    int w = tid >> 6, lane = tid & 63;
    int g = lane >> 4, mr = lane & 15;
    int e = texp[by], base = tpos[by], nv = tcnt[by];
    int bn = blockIdx.x * 64;
    if (tid < TM) tokS[tid] = sorted[base + min(tid, nv - 1)];
    __syncthreads();
    int mt = w >> 1, nbase = (w & 1) * 2;
    f32x4 acc[2] = {(f32x4){0.f,0.f,0.f,0.f}, (f32x4){0.f,0.f,0.f,0.f}};
    const ushort* We = aWT + (size_t)e * DD * DD;
    for (int k0 = 0; k0 < DD; k0 += 64) {
        {
            int r = tid >> 3, c8 = (tid & 7) * 8;
            *(short8*)&Al[r][c8] = *(const short8*)(hfullb + (size_t)tokS[r] * DD + k0 + c8);
        }
        #pragma unroll
        for (int i = 0; i < 2; ++i) {
            int c = tid + 256 * i;
            int r = c >> 3, c8 = (c & 7) * 8;
            *(short8*)&Bl[r][c8] = *(const short8*)(We + (size_t)(bn + r) * DD + k0 + c8);
        }
        __syncthreads();
        #pragma unroll
        for (int kk = 0; kk < 64; kk += 32) {
            short8 av = *(const short8*)&Al[16 * mt + mr][kk + g * 8];
            #pragma unroll
            for (int t = 0; t < 2; ++t) {
                short8 bv = *(const short8*)&Bl[16 * (nbase + t) + mr][kk + g * 8];
                acc[t] = __builtin_amdgcn_mfma_f32_16x16x32_bf16(av, bv, acc[t], 0, 0, 0);
            }
        }
        __syncthreads();
    }
    #pragma unroll
    for (int t = 0; t < 2; ++t) {
        int col = bn + 16 * (nbase + t) + mr;
        float abv = ab[(size_t)e * DD + col];
        #pragma unroll
        for (int r = 0; r < 4; ++r) {
            int row = 16 * mt + 4 * g + r;
            if (row < nv)
                yws[(size_t)tokS[row] * DD + col] = acc[t][r] + abv;
        }
    }
}

// ---- per-token LN(ag,abt)+gelu: yf fp32 + yb bf16 ----
__global__ __launch_bounds__(256) void k_yln(
    const float* __restrict__ yws, const float* __restrict__ ag,
    const float* __restrict__ abt, const int* __restrict__ levels,
    float* __restrict__ yf, ushort* __restrict__ yb) {
    int tok = blockIdx.x * 4 + (threadIdx.x >> 6);
    int lane = threadIdx.x & 63;
    int idx = min(max(levels[tok * 2], 0), NEXP - 1);
    float4 v = *(const float4*)(yws + (size_t)tok * DD + lane * 4);
    float s = v.x + v.y + v.z + v.w;
    float s2 = v.x * v.x + v.y * v.y + v.z * v.z + v.w * v.w;
    #pragma unroll
    for (int o = 1; o < 64; o <<= 1) { s += __shfl_xor(s, o); s2 += __shfl_xor(s2, o); }
    float m = s * (1.f / 256.f);
    float rs = rsqrtf(s2 * (1.f / 256.f) - m * m + 1e-5f);
    float4 g = *(const float4*)(ag + (size_t)idx * DD + lane * 4);
    float4 b = *(const float4*)(abt + (size_t)idx * DD + lane * 4);
    float4 y;
    y.x = gelu_f((v.x - m) * rs * g.x + b.x);
    y.y = gelu_f((v.y - m) * rs * g.y + b.y);
    y.z = gelu_f((v.z - m) * rs * g.z + b.z);
    y.w = gelu_f((v.w - m) * rs * g.w + b.w);
    *(float4*)(yf + (size_t)tok * DD + lane * 4) = y;
    ushort4 yb4 = {f2bf(y.x), f2bf(y.y), f2bf(y.z), f2bf(y.w)};
    *(ushort4*)(yb + (size_t)tok * DD + lane * 4) = yb4;
}

// ---- gate: p = g1[tok]·dw2; out = yf * (0.8 + 0.4*sigmoid(p+db2)) ----
__global__ __launch_bounds__(256) void k_gate(
    const float* __restrict__ yf, const ushort* __restrict__ g1,
    const float* __restrict__ dw2, const float* __restrict__ db2,
    float* __restrict__ out) {
    int tok = blockIdx.x * 4 + (threadIdx.x >> 6);
    int lane = threadIdx.x & 63;
    ushort2 gv = *(const ushort2*)(g1 + (size_t)tok * DHH + lane * 2);
    float2 w2 = *(const float2*)(dw2 + lane * 2);
    float p = bf2f(gv.x) * w2.x + bf2f(gv.y) * w2.y;
    #pragma unroll
    for (int o = 1; o < 64; o <<= 1) p += __shfl_xor(p, o);
    float gate = 0.8f + 0.4f / (1.f + expf(-(p + db2[0])));
    float4 y = *(const float4*)(yf + (size_t)tok * DD + lane * 4);
    y.x *= gate; y.y *= gate; y.z *= gate; y.w *= gate;
    *(float4*)(out + (size_t)tok * DD + lane * 4) = y;
}

extern "C" void kernel_launch(void* const* d_in, const int* in_sizes, int n_in,
                              void* d_out, int out_size, void* d_ws, size_t ws_size,
                              hipStream_t stream) {
    const float* tokens = (const float*)d_in[0];
    const float* ln_g = (const float*)d_in[1];
    const float* ln_b = (const float*)d_in[2];
    const float* pw1 = (const float*)d_in[3];
    const float* pb1 = (const float*)d_in[4];
    const float* pw2 = (const float*)d_in[5];
    const float* pb2 = (const float*)d_in[6];
    const float* emb = (const float*)d_in[7];
    const float* sw1 = (const float*)d_in[8];
    const float* sb1 = (const float*)d_in[9];
    const float* sw2 = (const float*)d_in[10];
    const float* sb2 = (const float*)d_in[11];
    const float* ew1 = (const float*)d_in[12];
    const float* eb1 = (const float*)d_in[13];
    const float* ew2 = (const float*)d_in[14];
    const float* eb2 = (const float*)d_in[15];
    const float* spw1 = (const float*)d_in[16];
    const float* spb1 = (const float*)d_in[17];
    const float* spw2 = (const float*)d_in[18];
    const float* spb2 = (const float*)d_in[19];
    const float* lw1 = (const float*)d_in[20];
    const float* lb1 = (const float*)d_in[21];
    const float* lw2 = (const float*)d_in[22];
    const float* lb2 = (const float*)d_in[23];
    const float* fw = (const float*)d_in[24];
    const float* fb = (const float*)d_in[25];
    const float* fg = (const float*)d_in[26];
    const float* fbeta = (const float*)d_in[27];
    const float* aW = (const float*)d_in[28];
    const float* ab = (const float*)d_in[29];
    const float* ag = (const float*)d_in[30];
    const float* abt = (const float*)d_in[31];
    const float* dw1 = (const float*)d_in[32];
    const float* db1 = (const float*)d_in[33];
    const float* dw2 = (const float*)d_in[34];
    const float* db2 = (const float*)d_in[35];
    const int* levels = (const int*)d_in[36];
    const int* ph = (const int*)d_in[37];
    const int* pw = (const int*)d_in[38];
    float* outp = (float*)d_out;

    char* wsb = (char*)d_ws;
    ushort* x_ln  = (ushort*)wsb;  wsb += (size_t)NTOK * IND * 2;
    ushort* h1    = (ushort*)wsb;  wsb += (size_t)NTOK * DD2 * 2;
    ushort* enh   = (ushort*)wsb;  wsb += (size_t)NTOK * DD * 2;
    float*  h     = (float*)wsb;   wsb += (size_t)NTOK * DD * 4;
    float*  e_pre = (float*)wsb;   wsb += (size_t)NTOK * DD * 4;
    ushort* hfullb = (ushort*)wsb; wsb += (size_t)NTOK * DD * 2;
    float*  yws   = (float*)wsb;   wsb += (size_t)NTOK * DD * 4;
    float*  yf    = (float*)wsb;   wsb += (size_t)NTOK * DD * 4;
    ushort* yb    = (ushort*)wsb;  wsb += (size_t)NTOK * DD * 2;
    ushort* g1    = (ushort*)wsb;  wsb += (size_t)NTOK * DHH * 2;
    ushort* pw1T  = (ushort*)wsb;  wsb += (size_t)DD2 * IND * 2;
    ushort* pw2T  = (ushort*)wsb;  wsb += (size_t)DD * DD2 * 2;
    ushort* fwT   = (ushort*)wsb;  wsb += (size_t)DD * DD * 2;
    ushort* aWT   = (ushort*)wsb;  wsb += (size_t)NEXP * DD * DD * 2;
    ushort* dw1T  = (ushort*)wsb;  wsb += (size_t)DHH * DD * 2;
    float*  constf = (float*)wsb;  wsb += 512;
    int*    sorted = (int*)wsb;    wsb += NTOK * 4;
    int*    tpos   = (int*)wsb;    wsb += NTILE_MAX * 4 + 4;
    int*    tcnt   = (int*)wsb;    wsb += NTILE_MAX * 4 + 4;
    int*    texp   = (int*)wsb;    wsb += NTILE_MAX * 4 + 4;
    int*    meta   = (int*)wsb;    wsb += 64;

    // 3,964,928 elements total -> 15488 blocks
    k_wconv<<<15488, 256, 0, stream>>>(pw1, pw2, fw, aW, dw1,
                                       pw1T, pw2T, fwT, aWT, dw1T);
    k_group<<<1, 1024, 0, stream>>>(levels, sorted, tpos, tcnt, texp, meta);
    k_const<<<1, 64, 0, stream>>>(spw1, spb1, spw2, spb2, lw1, lb1, lw2, lb2,
                                  levels, ph, pw, constf);
    k_stats<<<NTOK, 256, 0, stream>>>(tokens, ln_g, ln_b, sw1, sb1, sw2, sb2,
                                      ew1, eb1, ew2, eb2, constf, x_ln, enh);
    // h1 = gelu(x_ln @ pw1 + pb1) -> bf16
    k_mgemm<64><<<dim3(DD2 / 64, NTOK / 64), 256, 0, stream>>>(
        x_ln, pw1T, NTOK, DD2, IND, 1, pb1, nullptr, nullptr, nullptr, h1);
    // h = h1 @ pw2 + pb2 + emb[idx] -> f32
    k_mgemm<32><<<dim3(DD / 32, NTOK / 64), 256, 0, stream>>>(
        h1, pw2T, NTOK, DD, DD2, 2, pb2, levels, emb, h, nullptr);
    // e_pre = enh @ fw + fb -> f32
    k_mgemm<32><<<dim3(DD / 32, NTOK / 64), 256, 0, stream>>>(
        enh, fwT, NTOK, DD, DD, 0, fb, nullptr, nullptr, e_pre, nullptr);
    k_hfull<<<NTOK / 4, 256, 0, stream>>>(h, e_pre, fg, fbeta, hfullb);
    k_egemm<<<dim3(4, NTILE_MAX), 256, 0, stream>>>(
        hfullb, aWT, ab, sorted, tpos, tcnt, texp, meta, yws);
    k_yln<<<NTOK / 4, 256, 0, stream>>>(yws, ag, abt, levels, yf, yb);
    // g1 = relu(yb @ dw1 + db1) -> bf16
    k_mgemm<32><<<dim3(DHH / 32, NTOK / 64), 256, 0, stream>>>(
        yb, dw1T, NTOK, DHH, DD, 3, db1, nullptr, nullptr, nullptr, g1);
    k_gate<<<NTOK / 4, 256, 0, stream>>>(yf, g1, dw2, db2, outp);
}

// Round 6
// 94.818 us; speedup vs baseline: 8.3038x; 1.1594x over previous
//
#include <hip/hip_runtime.h>
#include <math.h>

#define NTOK 4096
#define IND 768
#define DD 256
#define DD2 512
#define DHH 128
#define NEXP 51
#define TM 32
#define NTILE_MAX 179   // floor(4096/32) + 51

typedef __attribute__((ext_vector_type(4))) float f32x4;
typedef __attribute__((ext_vector_type(8))) short short8;

__device__ __forceinline__ float gelu_f(float x) {
    return 0.5f * x * (1.0f + erff(x * 0.70710678118654752440f));
}
__device__ __forceinline__ ushort f2bf(float x) {
    unsigned u = __float_as_uint(x);
    return (ushort)((u + 0x7fffu + ((u >> 16) & 1u)) >> 16);
}
__device__ __forceinline__ float bf2f(ushort u) {
    return __uint_as_float((unsigned)u << 16);
}

// block-wide sum for 256 threads (4 waves)
__device__ __forceinline__ float block_sum(float v, float* lds) {
    #pragma unroll
    for (int o = 32; o > 0; o >>= 1) v += __shfl_down(v, o);
    int lane = threadIdx.x & 63, w = threadIdx.x >> 6;
    if (lane == 0) lds[w] = v;
    __syncthreads();
    float r = lds[0] + lds[1] + lds[2] + lds[3];
    __syncthreads();
    return r;
}

// ---- coalesced tiled transpose + bf16 convert for all weight matrices ----
// tile map: [0,96) pw1 768x512 ; [96,128) pw2 512x256 ; [128,144) fw 256x256 ;
//           [144,152) dw1 256x128 ; [152,968) aW per-expert 256x256
__global__ __launch_bounds__(256) void k_wconvT(
    const float* __restrict__ pw1, const float* __restrict__ pw2,
    const float* __restrict__ fw, const float* __restrict__ dw1,
    const float* __restrict__ aW,
    ushort* __restrict__ pw1T, ushort* __restrict__ pw2T, ushort* __restrict__ fwT,
    ushort* __restrict__ dw1T, ushort* __restrict__ aWT) {
    __shared__ float T[64][65];
    int b = blockIdx.x;
    const float* src; ushort* dst; int R, C;
    if (b < 96)       { src = pw1; dst = pw1T; R = IND; C = DD2; }
    else if (b < 128) { b -= 96;  src = pw2; dst = pw2T; R = DD2; C = DD; }
    else if (b < 144) { b -= 128; src = fw;  dst = fwT;  R = DD;  C = DD; }
    else if (b < 152) { b -= 144; src = dw1; dst = dw1T; R = DD;  C = DHH; }
    else { b -= 152; int e = b >> 4; b &= 15;
           src = aW + (size_t)e * DD * DD; dst = aWT + (size_t)e * DD * DD;
           R = DD; C = DD; }
    int tpc = C >> 6;
    int tr = b / tpc, tc = b - tr * tpc;
    int t = threadIdx.x;
    int lr = t >> 6, lc = t & 63;
    #pragma unroll
    for (int i = 0; i < 16; ++i) {
        int r = i * 4 + lr;
        T[r][lc] = src[(size_t)(tr * 64 + r) * C + tc * 64 + lc];
    }
    __syncthreads();
    #pragma unroll
    for (int i = 0; i < 16; ++i) {
        int r = i * 4 + lr;   // output row (= source col); read column of T
        dst[(size_t)(tc * 64 + r) * R + tr * 64 + lc] = f2bf(T[lc][r]);
    }
}

// ---- expert grouping (+ folded const-feat MLPs) ----
__global__ __launch_bounds__(1024) void k_group(
    const int* __restrict__ levels, int* __restrict__ sorted,
    int* __restrict__ tpos, int* __restrict__ tcnt, int* __restrict__ texp,
    int* __restrict__ meta,
    const float* __restrict__ spw1, const float* __restrict__ spb1,
    const float* __restrict__ spw2, const float* __restrict__ spb2,
    const float* __restrict__ lw1, const float* __restrict__ lb1,
    const float* __restrict__ lw2, const float* __restrict__ lb2,
    const int* __restrict__ ph, const int* __restrict__ pw,
    float* __restrict__ constf) {
    __shared__ int cnt[NEXP], cur[NEXP], offS[NEXP + 1], tileoff[NEXP + 1];
    __shared__ int expS[NTOK];
    __shared__ float hs[64], hl[64];
    int t = threadIdx.x;
    if (t < NEXP) cnt[t] = 0;
    if (t >= 64 && t < 128) {
        int j = t - 64;
        float p0 = (float)ph[0], p1 = (float)pw[0];
        float lvl = (float)levels[0];
        hs[j] = fmaxf(0.f, p0 * spw1[j] + p1 * spw1[64 + j] + spb1[j]);
        hl[j] = fmaxf(0.f, lvl * lw1[j] + lb1[j]);
    }
    __syncthreads();
    int myidx[4];
    #pragma unroll
    for (int i = 0; i < 4; ++i) {
        int n = t + i * 1024;
        int id = min(max(levels[n * 2], 0), NEXP - 1);
        myidx[i] = id;
        atomicAdd(&cnt[id], 1);
    }
    __syncthreads();
    if (t == 0) {
        int a = 0, ta = 0;
        for (int e = 0; e < NEXP; ++e) {
            offS[e] = a; cur[e] = a; tileoff[e] = ta;
            ta += (cnt[e] + TM - 1) / TM;
            a += cnt[e];
        }
        offS[NEXP] = a; tileoff[NEXP] = ta;
        meta[0] = ta;
    }
    if (t < 64) {
        float a = spb2[t], b2 = lb2[t];
        for (int j = 0; j < 64; ++j) {
            a  += hs[j] * spw2[j * 64 + t];
            b2 += hl[j] * lw2[j * 64 + t];
        }
        constf[t] = a;
        constf[64 + t] = b2;
    }
    __syncthreads();
    #pragma unroll
    for (int i = 0; i < 4; ++i) {
        int n = t + i * 1024;
        int p = atomicAdd(&cur[myidx[i]], 1);
        sorted[p] = n;
        expS[p] = myidx[i];
    }
    __syncthreads();
    #pragma unroll
    for (int i = 0; i < 4; ++i) {
        int p = t + i * 1024;
        int e = expS[p];
        int rel = p - offS[e];
        if ((rel & (TM - 1)) == 0) {
            int ti = tileoff[e] + (rel / TM);
            tpos[ti] = p;
            tcnt[ti] = min(TM, offS[e + 1] - p);
            texp[ti] = e;
        }
    }
}

// ---- per-token LN, stats, edge, stats/edge MLPs, enh assembly (bf16 outputs) ----
__global__ __launch_bounds__(256) void k_stats(
    const float* __restrict__ tokens,
    const float* __restrict__ ln_g, const float* __restrict__ ln_b,
    const float* __restrict__ sw1, const float* __restrict__ sb1,
    const float* __restrict__ sw2, const float* __restrict__ sb2,
    const float* __restrict__ ew1, const float* __restrict__ eb1,
    const float* __restrict__ ew2, const float* __restrict__ eb2,
    const float* __restrict__ constf,
    ushort* __restrict__ x_ln, ushort* __restrict__ enh) {
    int n = blockIdx.x, t = threadIdx.x;
    const float* x = tokens + (size_t)n * IND;
    __shared__ float red[4];
    float v[3];
    float s = 0.f, s2 = 0.f, es = 0.f;
    #pragma unroll
    for (int i = 0; i < 3; ++i) {
        int e = t + i * 256;
        float xv = x[e];
        v[i] = xv;
        s += xv; s2 += xv * xv;
        if (e > 0) es += fabsf(xv - x[e - 1]);
    }
    s  = block_sum(s, red);
    s2 = block_sum(s2, red);
    es = block_sum(es, red);
    float mean = s * (1.f / 768.f);
    float var_u = (s2 - 768.f * mean * mean) * (1.f / 767.f);
    float rstd = rsqrtf(s2 * (1.f / 768.f) - mean * mean + 1e-5f);
    float edge = es * (1.f / 767.f);
    #pragma unroll
    for (int i = 0; i < 3; ++i) {
        int e = t + i * 256;
        x_ln[(size_t)n * IND + e] = f2bf((v[i] - mean) * rstd * ln_g[e] + ln_b[e]);
    }
    __shared__ float hid[128];
    if (t < 64) {
        hid[t] = fmaxf(0.f, var_u * sw1[t] + mean * sw1[64 + t] + sb1[t]);
    } else if (t < 128) {
        int j = t - 64;
        hid[64 + j] = fmaxf(0.f, edge * ew1[j] + eb1[j]);
    }
    __syncthreads();
    ushort* er = enh + (size_t)n * DD;
    if (t < 64) {
        float a = sb2[t];
        for (int j = 0; j < 64; ++j) a += hid[j] * sw2[j * 64 + t];
        er[t] = f2bf(a);
    } else if (t < 128) {
        int k = t - 64;
        float a = eb2[k];
        for (int j = 0; j < 64; ++j) a += hid[64 + j] * ew2[j * 64 + k];
        er[64 + k] = f2bf(a);
    } else {
        er[t] = f2bf(constf[t - 128]);
    }
}

// ---- bf16 MFMA GEMM: C[M,N] = A[M,K] @ BT[N,K]^T, tile 64 x TN, BK=64 ----
// epi: 0 = v+bias -> f32; 1 = gelu(v+bias) -> bf16; 2 = v+bias+emb[idx] -> f32; 3 = relu(v+bias) -> bf16
template<int TN>
__global__ __launch_bounds__(256) void k_mgemm(
    const ushort* __restrict__ A, const ushort* __restrict__ BT,
    int M, int N, int K, int epi,
    const float* __restrict__ bias,
    const int* __restrict__ levels, const float* __restrict__ emb,
    float* __restrict__ Cf, ushort* __restrict__ Cb) {
    constexpr int NF = TN / 16;
    __shared__ ushort Al[64][72];
    __shared__ ushort Bl[TN][72];
    int tid = threadIdx.x;
    int w = tid >> 6, lane = tid & 63;
    int g = lane >> 4, mr = lane & 15;
    int bm = blockIdx.y * 64, bn = blockIdx.x * TN;
    f32x4 acc[NF];
    #pragma unroll
    for (int f = 0; f < NF; ++f) acc[f] = (f32x4){0.f, 0.f, 0.f, 0.f};
    for (int k0 = 0; k0 < K; k0 += 64) {
        #pragma unroll
        for (int i = 0; i < 2; ++i) {
            int c = tid + 256 * i;
            int r = c >> 3, c8 = (c & 7) * 8;
            *(short8*)&Al[r][c8] = *(const short8*)(A + (size_t)(bm + r) * K + k0 + c8);
        }
        #pragma unroll
        for (int i = 0; i < TN / 32; ++i) {
            int c = tid + 256 * i;
            int r = c >> 3, c8 = (c & 7) * 8;
            *(short8*)&Bl[r][c8] = *(const short8*)(BT + (size_t)(bn + r) * K + k0 + c8);
        }
        __syncthreads();
        #pragma unroll
        for (int kk = 0; kk < 64; kk += 32) {
            short8 av = *(const short8*)&Al[16 * w + mr][kk + g * 8];
            #pragma unroll
            for (int f = 0; f < NF; ++f) {
                short8 bv = *(const short8*)&Bl[16 * f + mr][kk + g * 8];
                acc[f] = __builtin_amdgcn_mfma_f32_16x16x32_bf16(av, bv, acc[f], 0, 0, 0);
            }
        }
        __syncthreads();
    }
    #pragma unroll
    for (int f = 0; f < NF; ++f) {
        int col = bn + 16 * f + mr;
        #pragma unroll
        for (int r = 0; r < 4; ++r) {
            int row = bm + 16 * w + 4 * g + r;
            float v = acc[f][r];
            if (epi == 1) {
                Cb[(size_t)row * N + col] = f2bf(gelu_f(v + bias[col]));
            } else if (epi == 3) {
                Cb[(size_t)row * N + col] = f2bf(fmaxf(v + bias[col], 0.f));
            } else if (epi == 2) {
                int id = min(max(levels[row * 2], 0), NEXP - 1);
                Cf[(size_t)row * N + col] = v + bias[col] + emb[(size_t)id * N + col];
            } else {
                Cf[(size_t)row * N + col] = v + bias[col];
            }
        }
    }
}

// ---- hfull(bf16) = h + 0.3*gelu(LN(e_pre; fg,fbeta)) ; one wave per token ----
__global__ __launch_bounds__(256) void k_hfull(
    const float* __restrict__ h, const float* __restrict__ e_pre,
    const float* __restrict__ fg, const float* __restrict__ fbeta,
    ushort* __restrict__ hfullb) {
    int tok = blockIdx.x * 4 + (threadIdx.x >> 6);
    int lane = threadIdx.x & 63;
    float4 e4 = *(const float4*)(e_pre + (size_t)tok * DD + lane * 4);
    float s = e4.x + e4.y + e4.z + e4.w;
    float s2 = e4.x * e4.x + e4.y * e4.y + e4.z * e4.z + e4.w * e4.w;
    #pragma unroll
    for (int o = 1; o < 64; o <<= 1) { s += __shfl_xor(s, o); s2 += __shfl_xor(s2, o); }
    float m = s * (1.f / 256.f);
    float rs = rsqrtf(s2 * (1.f / 256.f) - m * m + 1e-5f);
    float4 h4 = *(const float4*)(h + (size_t)tok * DD + lane * 4);
    float4 g4 = *(const float4*)(fg + lane * 4);
    float4 b4 = *(const float4*)(fbeta + lane * 4);
    ushort4 o4;
    o4.x = f2bf(h4.x + 0.3f * gelu_f((e4.x - m) * rs * g4.x + b4.x));
    o4.y = f2bf(h4.y + 0.3f * gelu_f((e4.y - m) * rs * g4.y + b4.y));
    o4.z = f2bf(h4.z + 0.3f * gelu_f((e4.z - m) * rs * g4.z + b4.z));
    o4.w = f2bf(h4.w + 0.3f * gelu_f((e4.w - m) * rs * g4.w + b4.w));
    *(ushort4*)(hfullb + (size_t)tok * DD + lane * 4) = o4;
}

// ---- grouped expert MFMA GEMM: y_pre[tok, :] = hfull[tok,:] @ aW[e] + ab[e] ----
__global__ __launch_bounds__(256) void k_egemm(
    const ushort* __restrict__ hfullb, const ushort* __restrict__ aWT,
    const float* __restrict__ ab,
    const int* __restrict__ sorted, const int* __restrict__ tpos,
    const int* __restrict__ tcnt, const int* __restrict__ texp,
    const int* __restrict__ meta,
    float* __restrict__ yws) {
    int by = blockIdx.y;
    if (by >= meta[0]) return;
    __shared__ ushort Al[TM][72];
    __shared__ ushort Bl[64][72];
    __shared__ int tokS[TM];
    int tid = threadIdx.x;
    int w = tid >> 6, lane = tid & 63;
    int g = lane >> 4, mr = lane & 15;
    int e = texp[by], base = tpos[by], nv = tcnt[by];
    int bn = blockIdx.x * 64;
    if (tid < TM) tokS[tid] = sorted[base + min(tid, nv - 1)];
    __syncthreads();
    int mt = w >> 1, nbase = (w & 1) * 2;
    f32x4 acc[2] = {(f32x4){0.f,0.f,0.f,0.f}, (f32x4){0.f,0.f,0.f,0.f}};
    const ushort* We = aWT + (size_t)e * DD * DD;
    for (int k0 = 0; k0 < DD; k0 += 64) {
        {
            int r = tid >> 3, c8 = (tid & 7) * 8;
            *(short8*)&Al[r][c8] = *(const short8*)(hfullb + (size_t)tokS[r] * DD + k0 + c8);
        }
        #pragma unroll
        for (int i = 0; i < 2; ++i) {
            int c = tid + 256 * i;
            int r = c >> 3, c8 = (c & 7) * 8;
            *(short8*)&Bl[r][c8] = *(const short8*)(We + (size_t)(bn + r) * DD + k0 + c8);
        }
        __syncthreads();
        #pragma unroll
        for (int kk = 0; kk < 64; kk += 32) {
            short8 av = *(const short8*)&Al[16 * mt + mr][kk + g * 8];
            #pragma unroll
            for (int t = 0; t < 2; ++t) {
                short8 bv = *(const short8*)&Bl[16 * (nbase + t) + mr][kk + g * 8];
                acc[t] = __builtin_amdgcn_mfma_f32_16x16x32_bf16(av, bv, acc[t], 0, 0, 0);
            }
        }
        __syncthreads();
    }
    #pragma unroll
    for (int t = 0; t < 2; ++t) {
        int col = bn + 16 * (nbase + t) + mr;
        float abv = ab[(size_t)e * DD + col];
        #pragma unroll
        for (int r = 0; r < 4; ++r) {
            int row = 16 * mt + 4 * g + r;
            if (row < nv)
                yws[(size_t)tokS[row] * DD + col] = acc[t][r] + abv;
        }
    }
}

// ---- per-token LN(ag,abt)+gelu: yf fp32 + yb bf16 ----
__global__ __launch_bounds__(256) void k_yln(
    const float* __restrict__ yws, const float* __restrict__ ag,
    const float* __restrict__ abt, const int* __restrict__ levels,
    float* __restrict__ yf, ushort* __restrict__ yb) {
    int tok = blockIdx.x * 4 + (threadIdx.x >> 6);
    int lane = threadIdx.x & 63;
    int idx = min(max(levels[tok * 2], 0), NEXP - 1);
    float4 v = *(const float4*)(yws + (size_t)tok * DD + lane * 4);
    float s = v.x + v.y + v.z + v.w;
    float s2 = v.x * v.x + v.y * v.y + v.z * v.z + v.w * v.w;
    #pragma unroll
    for (int o = 1; o < 64; o <<= 1) { s += __shfl_xor(s, o); s2 += __shfl_xor(s2, o); }
    float m = s * (1.f / 256.f);
    float rs = rsqrtf(s2 * (1.f / 256.f) - m * m + 1e-5f);
    float4 g = *(const float4*)(ag + (size_t)idx * DD + lane * 4);
    float4 b = *(const float4*)(abt + (size_t)idx * DD + lane * 4);
    float4 y;
    y.x = gelu_f((v.x - m) * rs * g.x + b.x);
    y.y = gelu_f((v.y - m) * rs * g.y + b.y);
    y.z = gelu_f((v.z - m) * rs * g.z + b.z);
    y.w = gelu_f((v.w - m) * rs * g.w + b.w);
    *(float4*)(yf + (size_t)tok * DD + lane * 4) = y;
    ushort4 yb4 = {f2bf(y.x), f2bf(y.y), f2bf(y.z), f2bf(y.w)};
    *(ushort4*)(yb + (size_t)tok * DD + lane * 4) = yb4;
}

// ---- gate: p = g1[tok]·dw2; out = yf * (0.8 + 0.4*sigmoid(p+db2)) ----
__global__ __launch_bounds__(256) void k_gate(
    const float* __restrict__ yf, const ushort* __restrict__ g1,
    const float* __restrict__ dw2, const float* __restrict__ db2,
    float* __restrict__ out) {
    int tok = blockIdx.x * 4 + (threadIdx.x >> 6);
    int lane = threadIdx.x & 63;
    ushort2 gv = *(const ushort2*)(g1 + (size_t)tok * DHH + lane * 2);
    float2 w2 = *(const float2*)(dw2 + lane * 2);
    float p = bf2f(gv.x) * w2.x + bf2f(gv.y) * w2.y;
    #pragma unroll
    for (int o = 1; o < 64; o <<= 1) p += __shfl_xor(p, o);
    float gate = 0.8f + 0.4f / (1.f + expf(-(p + db2[0])));
    float4 y = *(const float4*)(yf + (size_t)tok * DD + lane * 4);
    y.x *= gate; y.y *= gate; y.z *= gate; y.w *= gate;
    *(float4*)(out + (size_t)tok * DD + lane * 4) = y;
}

extern "C" void kernel_launch(void* const* d_in, const int* in_sizes, int n_in,
                              void* d_out, int out_size, void* d_ws, size_t ws_size,
                              hipStream_t stream) {
    const float* tokens = (const float*)d_in[0];
    const float* ln_g = (const float*)d_in[1];
    const float* ln_b = (const float*)d_in[2];
    const float* pw1 = (const float*)d_in[3];
    const float* pb1 = (const float*)d_in[4];
    const float* pw2 = (const float*)d_in[5];
    const float* pb2 = (const float*)d_in[6];
    const float* emb = (const float*)d_in[7];
    const float* sw1 = (const float*)d_in[8];
    const float* sb1 = (const float*)d_in[9];
    const float* sw2 = (const float*)d_in[10];
    const float* sb2 = (const float*)d_in[11];
    const float* ew1 = (const float*)d_in[12];
    const float* eb1 = (const float*)d_in[13];
    const float* ew2 = (const float*)d_in[14];
    const float* eb2 = (const float*)d_in[15];
    const float* spw1 = (const float*)d_in[16];
    const float* spb1 = (const float*)d_in[17];
    const float* spw2 = (const float*)d_in[18];
    const float* spb2 = (const float*)d_in[19];
    const float* lw1 = (const float*)d_in[20];
    const float* lb1 = (const float*)d_in[21];
    const float* lw2 = (const float*)d_in[22];
    const float* lb2 = (const float*)d_in[23];
    const float* fw = (const float*)d_in[24];
    const float* fb = (const float*)d_in[25];
    const float* fg = (const float*)d_in[26];
    const float* fbeta = (const float*)d_in[27];
    const float* aW = (const float*)d_in[28];
    const float* ab = (const float*)d_in[29];
    const float* ag = (const float*)d_in[30];
    const float* abt = (const float*)d_in[31];
    const float* dw1 = (const float*)d_in[32];
    const float* db1 = (const float*)d_in[33];
    const float* dw2 = (const float*)d_in[34];
    const float* db2 = (const float*)d_in[35];
    const int* levels = (const int*)d_in[36];
    const int* ph = (const int*)d_in[37];
    const int* pw = (const int*)d_in[38];
    float* outp = (float*)d_out;

    char* wsb = (char*)d_ws;
    ushort* x_ln  = (ushort*)wsb;  wsb += (size_t)NTOK * IND * 2;
    ushort* h1    = (ushort*)wsb;  wsb += (size_t)NTOK * DD2 * 2;
    ushort* enh   = (ushort*)wsb;  wsb += (size_t)NTOK * DD * 2;
    float*  h     = (float*)wsb;   wsb += (size_t)NTOK * DD * 4;
    float*  e_pre = (float*)wsb;   wsb += (size_t)NTOK * DD * 4;
    ushort* hfullb = (ushort*)wsb; wsb += (size_t)NTOK * DD * 2;
    float*  yws   = (float*)wsb;   wsb += (size_t)NTOK * DD * 4;
    float*  yf    = (float*)wsb;   wsb += (size_t)NTOK * DD * 4;
    ushort* yb    = (ushort*)wsb;  wsb += (size_t)NTOK * DD * 2;
    ushort* g1    = (ushort*)wsb;  wsb += (size_t)NTOK * DHH * 2;
    ushort* pw1T  = (ushort*)wsb;  wsb += (size_t)DD2 * IND * 2;
    ushort* pw2T  = (ushort*)wsb;  wsb += (size_t)DD * DD2 * 2;
    ushort* fwT   = (ushort*)wsb;  wsb += (size_t)DD * DD * 2;
    ushort* aWT   = (ushort*)wsb;  wsb += (size_t)NEXP * DD * DD * 2;
    ushort* dw1T  = (ushort*)wsb;  wsb += (size_t)DHH * DD * 2;
    float*  constf = (float*)wsb;  wsb += 512;
    int*    sorted = (int*)wsb;    wsb += NTOK * 4;
    int*    tpos   = (int*)wsb;    wsb += NTILE_MAX * 4 + 4;
    int*    tcnt   = (int*)wsb;    wsb += NTILE_MAX * 4 + 4;
    int*    texp   = (int*)wsb;    wsb += NTILE_MAX * 4 + 4;
    int*    meta   = (int*)wsb;    wsb += 64;

    k_wconvT<<<968, 256, 0, stream>>>(pw1, pw2, fw, dw1, aW,
                                      pw1T, pw2T, fwT, dw1T, aWT);
    k_group<<<1, 1024, 0, stream>>>(levels, sorted, tpos, tcnt, texp, meta,
                                    spw1, spb1, spw2, spb2, lw1, lb1, lw2, lb2,
                                    ph, pw, constf);
    k_stats<<<NTOK, 256, 0, stream>>>(tokens, ln_g, ln_b, sw1, sb1, sw2, sb2,
                                      ew1, eb1, ew2, eb2, constf, x_ln, enh);
    // h1 = gelu(x_ln @ pw1 + pb1) -> bf16
    k_mgemm<64><<<dim3(DD2 / 64, NTOK / 64), 256, 0, stream>>>(
        x_ln, pw1T, NTOK, DD2, IND, 1, pb1, nullptr, nullptr, nullptr, h1);
    // h = h1 @ pw2 + pb2 + emb[idx] -> f32
    k_mgemm<32><<<dim3(DD / 32, NTOK / 64), 256, 0, stream>>>(
        h1, pw2T, NTOK, DD, DD2, 2, pb2, levels, emb, h, nullptr);
    // e_pre = enh @ fw + fb -> f32
    k_mgemm<32><<<dim3(DD / 32, NTOK / 64), 256, 0, stream>>>(
        enh, fwT, NTOK, DD, DD, 0, fb, nullptr, nullptr, e_pre, nullptr);
    k_hfull<<<NTOK / 4, 256, 0, stream>>>(h, e_pre, fg, fbeta, hfullb);
    k_egemm<<<dim3(4, NTILE_MAX), 256, 0, stream>>>(
        hfullb, aWT, ab, sorted, tpos, tcnt, texp, meta, yws);
    k_yln<<<NTOK / 4, 256, 0, stream>>>(yws, ag, abt, levels, yf, yb);
    // g1 = relu(yb @ dw1 + db1) -> bf16
    k_mgemm<32><<<dim3(DHH / 32, NTOK / 64), 256, 0, stream>>>(
        yb, dw1T, NTOK, DHH, DD, 3, db1, nullptr, nullptr, nullptr, g1);
    k_gate<<<NTOK / 4, 256, 0, stream>>>(yf, g1, dw2, db2, outp);
}

// Round 7
// 89.034 us; speedup vs baseline: 8.8433x; 1.0650x over previous
//
#include <hip/hip_runtime.h>
#include <math.h>

#define NTOK 4096
#define IND 768
#define DD 256
#define DD2 512
#define DHH 128
#define NEXP 51
#define TM 32
#define NTILE_MAX 179   // floor(4096/32) + 51
#define NWCONV 968

typedef __attribute__((ext_vector_type(4))) float f32x4;
typedef __attribute__((ext_vector_type(8))) short short8;

__device__ __forceinline__ float gelu_f(float x) {
    return 0.5f * x * (1.0f + erff(x * 0.70710678118654752440f));
}
__device__ __forceinline__ ushort f2bf(float x) {
    unsigned u = __float_as_uint(x);
    return (ushort)((u + 0x7fffu + ((u >> 16) & 1u)) >> 16);
}
__device__ __forceinline__ float bf2f(ushort u) {
    return __uint_as_float((unsigned)u << 16);
}

// block-wide sum for 256 threads (4 waves)
__device__ __forceinline__ float block_sum(float v, float* lds) {
    #pragma unroll
    for (int o = 32; o > 0; o >>= 1) v += __shfl_down(v, o);
    int lane = threadIdx.x & 63, w = threadIdx.x >> 6;
    if (lane == 0) lds[w] = v;
    __syncthreads();
    float r = lds[0] + lds[1] + lds[2] + lds[3];
    __syncthreads();
    return r;
}

// ---- expert grouping (+ folded const-feat MLPs) ----
__global__ __launch_bounds__(1024) void k_group(
    const int* __restrict__ levels, int* __restrict__ sorted,
    int* __restrict__ tpos, int* __restrict__ tcnt, int* __restrict__ texp,
    int* __restrict__ meta,
    const float* __restrict__ spw1, const float* __restrict__ spb1,
    const float* __restrict__ spw2, const float* __restrict__ spb2,
    const float* __restrict__ lw1, const float* __restrict__ lb1,
    const float* __restrict__ lw2, const float* __restrict__ lb2,
    const int* __restrict__ ph, const int* __restrict__ pw,
    float* __restrict__ constf) {
    __shared__ int cnt[NEXP], cur[NEXP], offS[NEXP + 1], tileoff[NEXP + 1];
    __shared__ int expS[NTOK];
    __shared__ float hs[64], hl[64];
    int t = threadIdx.x;
    if (t < NEXP) cnt[t] = 0;
    if (t >= 64 && t < 128) {
        int j = t - 64;
        float p0 = (float)ph[0], p1 = (float)pw[0];
        float lvl = (float)levels[0];
        hs[j] = fmaxf(0.f, p0 * spw1[j] + p1 * spw1[64 + j] + spb1[j]);
        hl[j] = fmaxf(0.f, lvl * lw1[j] + lb1[j]);
    }
    __syncthreads();
    int myidx[4];
    #pragma unroll
    for (int i = 0; i < 4; ++i) {
        int n = t + i * 1024;
        int id = min(max(levels[n * 2], 0), NEXP - 1);
        myidx[i] = id;
        atomicAdd(&cnt[id], 1);
    }
    __syncthreads();
    if (t == 0) {
        int a = 0, ta = 0;
        for (int e = 0; e < NEXP; ++e) {
            offS[e] = a; cur[e] = a; tileoff[e] = ta;
            ta += (cnt[e] + TM - 1) / TM;
            a += cnt[e];
        }
        offS[NEXP] = a; tileoff[NEXP] = ta;
        meta[0] = ta;
    }
    if (t < 64) {
        float a = spb2[t], b2 = lb2[t];
        for (int j = 0; j < 64; ++j) {
            a  += hs[j] * spw2[j * 64 + t];
            b2 += hl[j] * lw2[j * 64 + t];
        }
        constf[t] = a;
        constf[64 + t] = b2;
    }
    __syncthreads();
    #pragma unroll
    for (int i = 0; i < 4; ++i) {
        int n = t + i * 1024;
        int p = atomicAdd(&cur[myidx[i]], 1);
        sorted[p] = n;
        expS[p] = myidx[i];
    }
    __syncthreads();
    #pragma unroll
    for (int i = 0; i < 4; ++i) {
        int p = t + i * 1024;
        int e = expS[p];
        int rel = p - offS[e];
        if ((rel & (TM - 1)) == 0) {
            int ti = tileoff[e] + (rel / TM);
            tpos[ti] = p;
            tcnt[ti] = min(TM, offS[e + 1] - p);
            texp[ti] = e;
        }
    }
}

// ---- fused: blocks [0,968) weight transpose+bf16 ; [968, 968+4096) per-token stats ----
__global__ __launch_bounds__(256) void k_pre(
    const float* __restrict__ pw1, const float* __restrict__ pw2,
    const float* __restrict__ fw, const float* __restrict__ dw1,
    const float* __restrict__ aW,
    ushort* __restrict__ pw1T, ushort* __restrict__ pw2T, ushort* __restrict__ fwT,
    ushort* __restrict__ dw1T, ushort* __restrict__ aWT,
    const float* __restrict__ tokens,
    const float* __restrict__ ln_g, const float* __restrict__ ln_b,
    const float* __restrict__ sw1, const float* __restrict__ sb1,
    const float* __restrict__ sw2, const float* __restrict__ sb2,
    const float* __restrict__ ew1, const float* __restrict__ eb1,
    const float* __restrict__ ew2, const float* __restrict__ eb2,
    const float* __restrict__ constf,
    ushort* __restrict__ x_ln, ushort* __restrict__ enh) {
    __shared__ float T[64][65];
    __shared__ float red[4];
    __shared__ float hid[128];
    if (blockIdx.x < NWCONV) {
        int b = blockIdx.x;
        const float* src; ushort* dst; int R, C;
        if (b < 96)       { src = pw1; dst = pw1T; R = IND; C = DD2; }
        else if (b < 128) { b -= 96;  src = pw2; dst = pw2T; R = DD2; C = DD; }
        else if (b < 144) { b -= 128; src = fw;  dst = fwT;  R = DD;  C = DD; }
        else if (b < 152) { b -= 144; src = dw1; dst = dw1T; R = DD;  C = DHH; }
        else { b -= 152; int e = b >> 4; b &= 15;
               src = aW + (size_t)e * DD * DD; dst = aWT + (size_t)e * DD * DD;
               R = DD; C = DD; }
        int tpc = C >> 6;
        int tr = b / tpc, tc = b - tr * tpc;
        int t = threadIdx.x;
        int lr = t >> 6, lc = t & 63;
        #pragma unroll
        for (int i = 0; i < 16; ++i) {
            int r = i * 4 + lr;
            T[r][lc] = src[(size_t)(tr * 64 + r) * C + tc * 64 + lc];
        }
        __syncthreads();
        #pragma unroll
        for (int i = 0; i < 16; ++i) {
            int r = i * 4 + lr;
            dst[(size_t)(tc * 64 + r) * R + tr * 64 + lc] = f2bf(T[lc][r]);
        }
        return;
    }
    int n = blockIdx.x - NWCONV, t = threadIdx.x;
    const float* x = tokens + (size_t)n * IND;
    float v[3];
    float s = 0.f, s2 = 0.f, es = 0.f;
    #pragma unroll
    for (int i = 0; i < 3; ++i) {
        int e = t + i * 256;
        float xv = x[e];
        v[i] = xv;
        s += xv; s2 += xv * xv;
        if (e > 0) es += fabsf(xv - x[e - 1]);
    }
    s  = block_sum(s, red);
    s2 = block_sum(s2, red);
    es = block_sum(es, red);
    float mean = s * (1.f / 768.f);
    float var_u = (s2 - 768.f * mean * mean) * (1.f / 767.f);
    float rstd = rsqrtf(s2 * (1.f / 768.f) - mean * mean + 1e-5f);
    float edge = es * (1.f / 767.f);
    #pragma unroll
    for (int i = 0; i < 3; ++i) {
        int e = t + i * 256;
        x_ln[(size_t)n * IND + e] = f2bf((v[i] - mean) * rstd * ln_g[e] + ln_b[e]);
    }
    if (t < 64) {
        hid[t] = fmaxf(0.f, var_u * sw1[t] + mean * sw1[64 + t] + sb1[t]);
    } else if (t < 128) {
        int j = t - 64;
        hid[64 + j] = fmaxf(0.f, edge * ew1[j] + eb1[j]);
    }
    __syncthreads();
    ushort* er = enh + (size_t)n * DD;
    if (t < 64) {
        float a = sb2[t];
        for (int j = 0; j < 64; ++j) a += hid[j] * sw2[j * 64 + t];
        er[t] = f2bf(a);
    } else if (t < 128) {
        int k = t - 64;
        float a = eb2[k];
        for (int j = 0; j < 64; ++j) a += hid[64 + j] * ew2[j * 64 + k];
        er[64 + k] = f2bf(a);
    } else {
        er[t] = f2bf(constf[t - 128]);
    }
}

// ---- bf16 MFMA GEMM1: h1 = gelu(x_ln @ pw1T^T + pb1), tile 64x64, BK=64 ----
__global__ __launch_bounds__(256) void k_mgemm1(
    const ushort* __restrict__ A, const ushort* __restrict__ BT,
    const float* __restrict__ bias, ushort* __restrict__ Cb) {
    const int N = DD2, K = IND;
    __shared__ ushort Al[64][72];
    __shared__ ushort Bl[64][72];
    int tid = threadIdx.x;
    int w = tid >> 6, lane = tid & 63;
    int g = lane >> 4, mr = lane & 15;
    int bm = blockIdx.y * 64, bn = blockIdx.x * 64;
    f32x4 acc[4];
    #pragma unroll
    for (int f = 0; f < 4; ++f) acc[f] = (f32x4){0.f, 0.f, 0.f, 0.f};
    for (int k0 = 0; k0 < K; k0 += 64) {
        #pragma unroll
        for (int i = 0; i < 2; ++i) {
            int c = tid + 256 * i;
            int r = c >> 3, c8 = (c & 7) * 8;
            *(short8*)&Al[r][c8] = *(const short8*)(A + (size_t)(bm + r) * K + k0 + c8);
        }
        #pragma unroll
        for (int i = 0; i < 2; ++i) {
            int c = tid + 256 * i;
            int r = c >> 3, c8 = (c & 7) * 8;
            *(short8*)&Bl[r][c8] = *(const short8*)(BT + (size_t)(bn + r) * K + k0 + c8);
        }
        __syncthreads();
        #pragma unroll
        for (int kk = 0; kk < 64; kk += 32) {
            short8 av = *(const short8*)&Al[16 * w + mr][kk + g * 8];
            #pragma unroll
            for (int f = 0; f < 4; ++f) {
                short8 bv = *(const short8*)&Bl[16 * f + mr][kk + g * 8];
                acc[f] = __builtin_amdgcn_mfma_f32_16x16x32_bf16(av, bv, acc[f], 0, 0, 0);
            }
        }
        __syncthreads();
    }
    #pragma unroll
    for (int f = 0; f < 4; ++f) {
        int col = bn + 16 * f + mr;
        float bv = bias[col];
        #pragma unroll
        for (int r = 0; r < 4; ++r) {
            int row = bm + 16 * w + 4 * g + r;
            Cb[(size_t)row * N + col] = f2bf(gelu_f(acc[f][r] + bv));
        }
    }
}

// ---- fused GEMM2+GEMM3: by<64: h = h1@pw2T^T + pb2 + emb[idx]; else e_pre = enh@fwT^T + fb ----
__global__ __launch_bounds__(256) void k_mid(
    const ushort* __restrict__ h1, const ushort* __restrict__ pw2T,
    const float* __restrict__ pb2, const int* __restrict__ levels,
    const float* __restrict__ emb, float* __restrict__ h,
    const ushort* __restrict__ enh, const ushort* __restrict__ fwT,
    const float* __restrict__ fb, float* __restrict__ e_pre) {
    __shared__ ushort Al[64][72];
    __shared__ ushort Bl[32][72];
    int by = blockIdx.y;
    const ushort* A; const ushort* BT; const float* bias; float* Cf;
    int K, epi, bm;
    if (by < 64) { A = h1; BT = pw2T; bias = pb2; Cf = h; K = DD2; epi = 2; bm = by * 64; }
    else         { A = enh; BT = fwT; bias = fb; Cf = e_pre; K = DD; epi = 0; bm = (by - 64) * 64; }
    int tid = threadIdx.x;
    int w = tid >> 6, lane = tid & 63;
    int g = lane >> 4, mr = lane & 15;
    int bn = blockIdx.x * 32;
    f32x4 acc[2];
    acc[0] = (f32x4){0.f, 0.f, 0.f, 0.f};
    acc[1] = (f32x4){0.f, 0.f, 0.f, 0.f};
    for (int k0 = 0; k0 < K; k0 += 64) {
        #pragma unroll
        for (int i = 0; i < 2; ++i) {
            int c = tid + 256 * i;
            int r = c >> 3, c8 = (c & 7) * 8;
            *(short8*)&Al[r][c8] = *(const short8*)(A + (size_t)(bm + r) * K + k0 + c8);
        }
        {
            int r = tid >> 3, c8 = (tid & 7) * 8;
            *(short8*)&Bl[r][c8] = *(const short8*)(BT + (size_t)(bn + r) * K + k0 + c8);
        }
        __syncthreads();
        #pragma unroll
        for (int kk = 0; kk < 64; kk += 32) {
            short8 av = *(const short8*)&Al[16 * w + mr][kk + g * 8];
            #pragma unroll
            for (int f = 0; f < 2; ++f) {
                short8 bv = *(const short8*)&Bl[16 * f + mr][kk + g * 8];
                acc[f] = __builtin_amdgcn_mfma_f32_16x16x32_bf16(av, bv, acc[f], 0, 0, 0);
            }
        }
        __syncthreads();
    }
    #pragma unroll
    for (int f = 0; f < 2; ++f) {
        int col = bn + 16 * f + mr;
        float bv = bias[col];
        #pragma unroll
        for (int r = 0; r < 4; ++r) {
            int row = bm + 16 * w + 4 * g + r;
            float v = acc[f][r] + bv;
            if (epi == 2) {
                int id = min(max(levels[row * 2], 0), NEXP - 1);
                v += emb[(size_t)id * DD + col];
            }
            Cf[(size_t)row * DD + col] = v;
        }
    }
}

// ---- fully fused adapter: hfull -> expert GEMM -> LN+gelu -> gate GEMM -> out ----
__global__ __launch_bounds__(256) void k_adapterF(
    const float* __restrict__ h, const float* __restrict__ e_pre,
    const float* __restrict__ fg, const float* __restrict__ fbeta,
    const ushort* __restrict__ aWT, const float* __restrict__ ab,
    const float* __restrict__ ag, const float* __restrict__ abt,
    const ushort* __restrict__ dw1T, const float* __restrict__ db1,
    const float* __restrict__ dw2, const float* __restrict__ db2,
    const int* __restrict__ sorted, const int* __restrict__ tpos,
    const int* __restrict__ tcnt, const int* __restrict__ texp,
    const int* __restrict__ meta, float* __restrict__ out) {
    __shared__ __align__(16) ushort Alf[TM][264];    // hfull (bf16), later y (bf16)
    __shared__ __align__(16) char BlRaw[256 * 72 * 2]; // expert B chunks; later yf32[32][260]
    __shared__ __align__(16) ushort Dl[DHH][72];
    __shared__ int tokS[TM];
    __shared__ float gateS[TM];
    __shared__ float pg[4][TM];
    int b = blockIdx.x;
    if (b >= meta[0]) return;
    int tid = threadIdx.x, w = tid >> 6, lane = tid & 63;
    int g = lane >> 4, mr = lane & 15;
    int e = texp[b], base = tpos[b], nv = tcnt[b];
    if (tid < TM) tokS[tid] = sorted[base + min(tid, nv - 1)];
    __syncthreads();
    // phase 1: hfull = h + 0.3*gelu(LN(e_pre; fg,fbeta)) -> Alf bf16; wave per 8 rows
    #pragma unroll
    for (int i = 0; i < 8; ++i) {
        int r = w * 8 + i;
        int tok = tokS[r];
        float4 e4 = *(const float4*)(e_pre + (size_t)tok * DD + lane * 4);
        float s = e4.x + e4.y + e4.z + e4.w;
        float s2 = e4.x * e4.x + e4.y * e4.y + e4.z * e4.z + e4.w * e4.w;
        #pragma unroll
        for (int o = 1; o < 64; o <<= 1) { s += __shfl_xor(s, o); s2 += __shfl_xor(s2, o); }
        float m = s * (1.f / 256.f);
        float rs = rsqrtf(s2 * (1.f / 256.f) - m * m + 1e-5f);
        float4 h4 = *(const float4*)(h + (size_t)tok * DD + lane * 4);
        float4 g4 = *(const float4*)(fg + lane * 4);
        float4 b4 = *(const float4*)(fbeta + lane * 4);
        ushort4 o4;
        o4.x = f2bf(h4.x + 0.3f * gelu_f((e4.x - m) * rs * g4.x + b4.x));
        o4.y = f2bf(h4.y + 0.3f * gelu_f((e4.y - m) * rs * g4.y + b4.y));
        o4.z = f2bf(h4.z + 0.3f * gelu_f((e4.z - m) * rs * g4.z + b4.z));
        o4.w = f2bf(h4.w + 0.3f * gelu_f((e4.w - m) * rs * g4.w + b4.w));
        *(ushort4*)&Alf[r][lane * 4] = o4;
    }
    __syncthreads();
    // phase 2: expert GEMM acc[32 x 256] = hfull @ aWT[e]^T
    ushort* Bl = (ushort*)BlRaw;       // [256][72]
    const ushort* We = aWT + (size_t)e * DD * DD;
    int mt = w & 1, nfh = w >> 1;      // wave: rows 16mt.., cols 128nfh..
    f32x4 acc[8];
    #pragma unroll
    for (int t = 0; t < 8; ++t) acc[t] = (f32x4){0.f, 0.f, 0.f, 0.f};
    for (int k0 = 0; k0 < DD; k0 += 64) {
        #pragma unroll
        for (int i = 0; i < 8; ++i) {
            int c = tid + 256 * i;
            int r = c >> 3, c8 = (c & 7) * 8;
            *(short8*)&Bl[r * 72 + c8] = *(const short8*)(We + (size_t)r * DD + k0 + c8);
        }
        __syncthreads();
        #pragma unroll
        for (int kk = 0; kk < 64; kk += 32) {
            short8 av = *(const short8*)&Alf[16 * mt + mr][k0 + kk + g * 8];
            #pragma unroll
            for (int t = 0; t < 8; ++t) {
                short8 bv = *(const short8*)&Bl[(128 * nfh + 16 * t + mr) * 72 + kk + g * 8];
                acc[t] = __builtin_amdgcn_mfma_f32_16x16x32_bf16(av, bv, acc[t], 0, 0, 0);
            }
        }
        __syncthreads();
    }
    // phase 3: yf32 = acc + ab  (Bl space is free now)
    float* yf32 = (float*)BlRaw;       // [32][260]
    #pragma unroll
    for (int t = 0; t < 8; ++t) {
        int col = 128 * nfh + 16 * t + mr;
        float abv = ab[(size_t)e * DD + col];
        #pragma unroll
        for (int r = 0; r < 4; ++r) {
            int row = 16 * mt + 4 * g + r;
            yf32[row * 260 + col] = acc[t][r] + abv;
        }
    }
    __syncthreads();
    // phase 4: per-row LN(ag,abt)+gelu; y -> yf32 (in place) and bf16 -> Alf
    #pragma unroll
    for (int i = 0; i < 8; ++i) {
        int r = w * 8 + i;
        float4 v = *(const float4*)&yf32[r * 260 + lane * 4];
        float s = v.x + v.y + v.z + v.w;
        float s2 = v.x * v.x + v.y * v.y + v.z * v.z + v.w * v.w;
        #pragma unroll
        for (int o = 1; o < 64; o <<= 1) { s += __shfl_xor(s, o); s2 += __shfl_xor(s2, o); }
        float m = s * (1.f / 256.f);
        float rs = rsqrtf(s2 * (1.f / 256.f) - m * m + 1e-5f);
        float4 gg = *(const float4*)(ag + (size_t)e * DD + lane * 4);
        float4 bb = *(const float4*)(abt + (size_t)e * DD + lane * 4);
        float4 y;
        y.x = gelu_f((v.x - m) * rs * gg.x + bb.x);
        y.y = gelu_f((v.y - m) * rs * gg.y + bb.y);
        y.z = gelu_f((v.z - m) * rs * gg.z + bb.z);
        y.w = gelu_f((v.w - m) * rs * gg.w + bb.w);
        *(float4*)&yf32[r * 260 + lane * 4] = y;
        ushort4 o4 = {f2bf(y.x), f2bf(y.y), f2bf(y.z), f2bf(y.w)};
        *(ushort4*)&Alf[r][lane * 4] = o4;
    }
    __syncthreads();
    // phase 5: gate GEMM g[32x128] = y_bf @ dw1T^T; wave w -> col frags {2w,2w+1}, both row frags
    f32x4 acc2[2][2];
    #pragma unroll
    for (int a = 0; a < 2; ++a) { acc2[a][0] = (f32x4){0,0,0,0}; acc2[a][1] = (f32x4){0,0,0,0}; }
    for (int k0 = 0; k0 < DD; k0 += 64) {
        #pragma unroll
        for (int i = 0; i < 4; ++i) {
            int c = tid + 256 * i;
            int r = c >> 3, c8 = (c & 7) * 8;
            *(short8*)&Dl[r][c8] = *(const short8*)(dw1T + (size_t)r * DD + k0 + c8);
        }
        __syncthreads();
        #pragma unroll
        for (int kk = 0; kk < 64; kk += 32) {
            #pragma unroll
            for (int a = 0; a < 2; ++a) {
                short8 av = *(const short8*)&Alf[16 * a + mr][k0 + kk + g * 8];
                #pragma unroll
                for (int t = 0; t < 2; ++t) {
                    short8 bv = *(const short8*)&Dl[16 * (2 * w + t) + mr][kk + g * 8];
                    acc2[a][t] = __builtin_amdgcn_mfma_f32_16x16x32_bf16(av, bv, acc2[a][t], 0, 0, 0);
                }
            }
        }
        __syncthreads();
    }
    // phase 6: p[row] = sum_col relu(g+db1)*dw2
    float pv[2][4] = {};
    #pragma unroll
    for (int t = 0; t < 2; ++t) {
        int col = 32 * w + 16 * t + mr;
        float d1 = db1[col], d2 = dw2[col];
        #pragma unroll
        for (int a = 0; a < 2; ++a)
            #pragma unroll
            for (int r = 0; r < 4; ++r)
                pv[a][r] += fmaxf(acc2[a][t][r] + d1, 0.f) * d2;
    }
    #pragma unroll
    for (int o = 1; o < 16; o <<= 1) {
        #pragma unroll
        for (int a = 0; a < 2; ++a)
            #pragma unroll
            for (int r = 0; r < 4; ++r)
                pv[a][r] += __shfl_xor(pv[a][r], o);
    }
    if (mr == 0) {
        #pragma unroll
        for (int a = 0; a < 2; ++a)
            #pragma unroll
            for (int r = 0; r < 4; ++r)
                pg[w][16 * a + 4 * g + r] = pv[a][r];
    }
    __syncthreads();
    if (tid < TM) {
        float p = pg[0][tid] + pg[1][tid] + pg[2][tid] + pg[3][tid] + db2[0];
        gateS[tid] = 0.8f + 0.4f / (1.f + expf(-p));
    }
    __syncthreads();
    // phase 7: out = y * gate, scatter
    int row = tid >> 3, c0 = (tid & 7) * 32;
    if (row < nv) {
        int tok = tokS[row];
        float gt = gateS[row];
        #pragma unroll
        for (int j = 0; j < 8; ++j) {
            float4 v = *(const float4*)&yf32[row * 260 + c0 + j * 4];
            v.x *= gt; v.y *= gt; v.z *= gt; v.w *= gt;
            *(float4*)(out + (size_t)tok * DD + c0 + j * 4) = v;
        }
    }
}

extern "C" void kernel_launch(void* const* d_in, const int* in_sizes, int n_in,
                              void* d_out, int out_size, void* d_ws, size_t ws_size,
                              hipStream_t stream) {
    const float* tokens = (const float*)d_in[0];
    const float* ln_g = (const float*)d_in[1];
    const float* ln_b = (const float*)d_in[2];
    const float* pw1 = (const float*)d_in[3];
    const float* pb1 = (const float*)d_in[4];
    const float* pw2 = (const float*)d_in[5];
    const float* pb2 = (const float*)d_in[6];
    const float* emb = (const float*)d_in[7];
    const float* sw1 = (const float*)d_in[8];
    const float* sb1 = (const float*)d_in[9];
    const float* sw2 = (const float*)d_in[10];
    const float* sb2 = (const float*)d_in[11];
    const float* ew1 = (const float*)d_in[12];
    const float* eb1 = (const float*)d_in[13];
    const float* ew2 = (const float*)d_in[14];
    const float* eb2 = (const float*)d_in[15];
    const float* spw1 = (const float*)d_in[16];
    const float* spb1 = (const float*)d_in[17];
    const float* spw2 = (const float*)d_in[18];
    const float* spb2 = (const float*)d_in[19];
    const float* lw1 = (const float*)d_in[20];
    const float* lb1 = (const float*)d_in[21];
    const float* lw2 = (const float*)d_in[22];
    const float* lb2 = (const float*)d_in[23];
    const float* fw = (const float*)d_in[24];
    const float* fb = (const float*)d_in[25];
    const float* fg = (const float*)d_in[26];
    const float* fbeta = (const float*)d_in[27];
    const float* aW = (const float*)d_in[28];
    const float* ab = (const float*)d_in[29];
    const float* ag = (const float*)d_in[30];
    const float* abt = (const float*)d_in[31];
    const float* dw1 = (const float*)d_in[32];
    const float* db1 = (const float*)d_in[33];
    const float* dw2 = (const float*)d_in[34];
    const float* db2 = (const float*)d_in[35];
    const int* levels = (const int*)d_in[36];
    const int* ph = (const int*)d_in[37];
    const int* pw = (const int*)d_in[38];
    float* outp = (float*)d_out;

    char* wsb = (char*)d_ws;
    ushort* x_ln  = (ushort*)wsb;  wsb += (size_t)NTOK * IND * 2;
    ushort* h1    = (ushort*)wsb;  wsb += (size_t)NTOK * DD2 * 2;
    ushort* enh   = (ushort*)wsb;  wsb += (size_t)NTOK * DD * 2;
    float*  h     = (float*)wsb;   wsb += (size_t)NTOK * DD * 4;
    float*  e_pre = (float*)wsb;   wsb += (size_t)NTOK * DD * 4;
    ushort* pw1T  = (ushort*)wsb;  wsb += (size_t)DD2 * IND * 2;
    ushort* pw2T  = (ushort*)wsb;  wsb += (size_t)DD * DD2 * 2;
    ushort* fwT   = (ushort*)wsb;  wsb += (size_t)DD * DD * 2;
    ushort* aWT   = (ushort*)wsb;  wsb += (size_t)NEXP * DD * DD * 2;
    ushort* dw1T  = (ushort*)wsb;  wsb += (size_t)DHH * DD * 2;
    float*  constf = (float*)wsb;  wsb += 512;
    int*    sorted = (int*)wsb;    wsb += NTOK * 4;
    int*    tpos   = (int*)wsb;    wsb += NTILE_MAX * 4 + 4;
    int*    tcnt   = (int*)wsb;    wsb += NTILE_MAX * 4 + 4;
    int*    texp   = (int*)wsb;    wsb += NTILE_MAX * 4 + 4;
    int*    meta   = (int*)wsb;    wsb += 64;

    k_group<<<1, 1024, 0, stream>>>(levels, sorted, tpos, tcnt, texp, meta,
                                    spw1, spb1, spw2, spb2, lw1, lb1, lw2, lb2,
                                    ph, pw, constf);
    k_pre<<<NWCONV + NTOK, 256, 0, stream>>>(
        pw1, pw2, fw, dw1, aW, pw1T, pw2T, fwT, dw1T, aWT,
        tokens, ln_g, ln_b, sw1, sb1, sw2, sb2, ew1, eb1, ew2, eb2,
        constf, x_ln, enh);
    k_mgemm1<<<dim3(DD2 / 64, NTOK / 64), 256, 0, stream>>>(x_ln, pw1T, pb1, h1);
    k_mid<<<dim3(DD / 32, 128), 256, 0, stream>>>(
        h1, pw2T, pb2, levels, emb, h, enh, fwT, fb, e_pre);
    k_adapterF<<<NTILE_MAX, 256, 0, stream>>>(
        h, e_pre, fg, fbeta, aWT, ab, ag, abt, dw1T, db1, dw2, db2,
        sorted, tpos, tcnt, texp, meta, outp);
}

// Round 8
// 85.178 us; speedup vs baseline: 9.2436x; 1.0453x over previous
//
#include <hip/hip_runtime.h>
#include <math.h>

#define NTOK 4096
#define IND 768
#define DD 256
#define DD2 512
#define DHH 128
#define NEXP 51
#define TM 32
#define NTILE_MAX 179   // floor(4096/32) + 51
#define NWCONV 968

typedef __attribute__((ext_vector_type(4))) float f32x4;
typedef __attribute__((ext_vector_type(8))) short short8;

__device__ __forceinline__ float gelu_f(float x) {
    return 0.5f * x * (1.0f + erff(x * 0.70710678118654752440f));
}
__device__ __forceinline__ ushort f2bf(float x) {
    unsigned u = __float_as_uint(x);
    return (ushort)((u + 0x7fffu + ((u >> 16) & 1u)) >> 16);
}

// block-wide sum for 256 threads (4 waves)
__device__ __forceinline__ float block_sum(float v, float* lds) {
    #pragma unroll
    for (int o = 32; o > 0; o >>= 1) v += __shfl_down(v, o);
    int lane = threadIdx.x & 63, w = threadIdx.x >> 6;
    if (lane == 0) lds[w] = v;
    __syncthreads();
    float r = lds[0] + lds[1] + lds[2] + lds[3];
    __syncthreads();
    return r;
}

// ---- fused pre-pass ----
// block 0: grouping + tile build + const-feat MLPs + ctail
// blocks [1, 1+NWCONV): weight transpose + bf16 convert
// blocks [1+NWCONV, 1+NWCONV+NTOK): per-token stats (x_ln, enh[0:128])
__global__ __launch_bounds__(256) void k_pre(
    const float* __restrict__ pw1, const float* __restrict__ pw2,
    const float* __restrict__ fw, const float* __restrict__ dw1,
    const float* __restrict__ aW,
    ushort* __restrict__ pw1T, ushort* __restrict__ pw2T, ushort* __restrict__ fwT,
    ushort* __restrict__ dw1T, ushort* __restrict__ aWT,
    const float* __restrict__ tokens,
    const float* __restrict__ ln_g, const float* __restrict__ ln_b,
    const float* __restrict__ sw1, const float* __restrict__ sb1,
    const float* __restrict__ sw2, const float* __restrict__ sb2,
    const float* __restrict__ ew1, const float* __restrict__ eb1,
    const float* __restrict__ ew2, const float* __restrict__ eb2,
    ushort* __restrict__ x_ln, ushort* __restrict__ enh,
    const int* __restrict__ levels,
    const float* __restrict__ spw1, const float* __restrict__ spb1,
    const float* __restrict__ spw2, const float* __restrict__ spb2,
    const float* __restrict__ lw1, const float* __restrict__ lb1,
    const float* __restrict__ lw2, const float* __restrict__ lb2,
    const int* __restrict__ ph, const int* __restrict__ pw,
    const float* __restrict__ fb,
    int* __restrict__ sorted, int* __restrict__ tpos, int* __restrict__ tcnt,
    int* __restrict__ texp, int* __restrict__ meta, float* __restrict__ ctail) {
    __shared__ float T[64][65];
    __shared__ float red[4];
    __shared__ float hid[128];
    __shared__ int cnt[NEXP], cur[NEXP], offS[NEXP + 1], tileoff[NEXP + 1];
    __shared__ int expS[NTOK];
    __shared__ float hs[64], hl[64], cf[128];
    int t = threadIdx.x;

    if (blockIdx.x == 0) {
        // --- grouping + const feats + ctail ---
        if (t < NEXP) cnt[t] = 0;
        if (t < 64) {
            float p0 = (float)ph[0], p1 = (float)pw[0];
            float lvl = (float)levels[0];
            hs[t] = fmaxf(0.f, p0 * spw1[t] + p1 * spw1[64 + t] + spb1[t]);
            hl[t] = fmaxf(0.f, lvl * lw1[t] + lb1[t]);
        }
        __syncthreads();
        int myidx[16];
        #pragma unroll
        for (int i = 0; i < 16; ++i) {
            int n = t + i * 256;
            int id = min(max(levels[n * 2], 0), NEXP - 1);
            myidx[i] = id;
            atomicAdd(&cnt[id], 1);
        }
        if (t < 64) {
            float a = spb2[t];
            for (int j = 0; j < 64; ++j) a += hs[j] * spw2[j * 64 + t];
            cf[t] = a;
        } else if (t < 128) {
            int k = t - 64;
            float a = lb2[k];
            for (int j = 0; j < 64; ++j) a += hl[j] * lw2[j * 64 + k];
            cf[64 + k] = a;
        }
        __syncthreads();
        if (t == 0) {
            int a = 0, ta = 0;
            for (int e = 0; e < NEXP; ++e) {
                offS[e] = a; cur[e] = a; tileoff[e] = ta;
                ta += (cnt[e] + TM - 1) / TM;
                a += cnt[e];
            }
            offS[NEXP] = a; tileoff[NEXP] = ta;
            meta[0] = ta;
        }
        __syncthreads();
        #pragma unroll
        for (int i = 0; i < 16; ++i) {
            int n = t + i * 256;
            int p = atomicAdd(&cur[myidx[i]], 1);
            sorted[p] = n;
            expS[p] = myidx[i];
        }
        // ctail[c] = fb[c] + sum_{j<128} cf[j]*fw[128+j][c]  (spatial|level tail)
        {
            float a = fb[t];
            for (int j = 0; j < 128; ++j) a += cf[j] * fw[(size_t)(128 + j) * DD + t];
            ctail[t] = a;
        }
        __syncthreads();
        #pragma unroll
        for (int i = 0; i < 16; ++i) {
            int p = t + i * 256;
            int e = expS[p];
            int rel = p - offS[e];
            if ((rel & (TM - 1)) == 0) {
                int ti = tileoff[e] + (rel / TM);
                tpos[ti] = p;
                tcnt[ti] = min(TM, offS[e + 1] - p);
                texp[ti] = e;
            }
        }
        return;
    }
    if (blockIdx.x < 1 + NWCONV) {
        // --- transpose + bf16 ---
        int b = blockIdx.x - 1;
        const float* src; ushort* dst; int R, C;
        if (b < 96)       { src = pw1; dst = pw1T; R = IND; C = DD2; }
        else if (b < 128) { b -= 96;  src = pw2; dst = pw2T; R = DD2; C = DD; }
        else if (b < 144) { b -= 128; src = fw;  dst = fwT;  R = DD;  C = DD; }
        else if (b < 152) { b -= 144; src = dw1; dst = dw1T; R = DD;  C = DHH; }
        else { b -= 152; int e = b >> 4; b &= 15;
               src = aW + (size_t)e * DD * DD; dst = aWT + (size_t)e * DD * DD;
               R = DD; C = DD; }
        int tpc = C >> 6;
        int tr = b / tpc, tc = b - tr * tpc;
        int lr = t >> 6, lc = t & 63;
        #pragma unroll
        for (int i = 0; i < 16; ++i) {
            int r = i * 4 + lr;
            T[r][lc] = src[(size_t)(tr * 64 + r) * C + tc * 64 + lc];
        }
        __syncthreads();
        #pragma unroll
        for (int i = 0; i < 16; ++i) {
            int r = i * 4 + lr;
            dst[(size_t)(tc * 64 + r) * R + tr * 64 + lc] = f2bf(T[lc][r]);
        }
        return;
    }
    // --- per-token stats ---
    int n = blockIdx.x - 1 - NWCONV;
    const float* x = tokens + (size_t)n * IND;
    float v[3];
    float s = 0.f, s2 = 0.f, es = 0.f;
    #pragma unroll
    for (int i = 0; i < 3; ++i) {
        int e = t + i * 256;
        float xv = x[e];
        v[i] = xv;
        s += xv; s2 += xv * xv;
        if (e > 0) es += fabsf(xv - x[e - 1]);
    }
    s  = block_sum(s, red);
    s2 = block_sum(s2, red);
    es = block_sum(es, red);
    float mean = s * (1.f / 768.f);
    float var_u = (s2 - 768.f * mean * mean) * (1.f / 767.f);
    float rstd = rsqrtf(s2 * (1.f / 768.f) - mean * mean + 1e-5f);
    float edge = es * (1.f / 767.f);
    #pragma unroll
    for (int i = 0; i < 3; ++i) {
        int e = t + i * 256;
        x_ln[(size_t)n * IND + e] = f2bf((v[i] - mean) * rstd * ln_g[e] + ln_b[e]);
    }
    if (t < 64) {
        hid[t] = fmaxf(0.f, var_u * sw1[t] + mean * sw1[64 + t] + sb1[t]);
    } else if (t < 128) {
        int j = t - 64;
        hid[64 + j] = fmaxf(0.f, edge * ew1[j] + eb1[j]);
    }
    __syncthreads();
    ushort* er = enh + (size_t)n * DHH;   // enh is [NTOK][128] now
    if (t < 64) {
        float a = sb2[t];
        for (int j = 0; j < 64; ++j) a += hid[j] * sw2[j * 64 + t];
        er[t] = f2bf(a);
    } else if (t < 128) {
        int k = t - 64;
        float a = eb2[k];
        for (int j = 0; j < 64; ++j) a += hid[64 + j] * ew2[j * 64 + k];
        er[64 + k] = f2bf(a);
    }
}

// ---- bf16 MFMA GEMM1: h1 = gelu(x_ln @ pw1T^T + pb1), tile 64x64, BK=64 ----
__global__ __launch_bounds__(256) void k_gemm1(
    const ushort* __restrict__ A, const ushort* __restrict__ BT,
    const float* __restrict__ bias, ushort* __restrict__ Cb) {
    const int N = DD2, K = IND;
    __shared__ ushort Al[64][72];
    __shared__ ushort Bl[64][72];
    int tid = threadIdx.x;
    int w = tid >> 6, lane = tid & 63;
    int g = lane >> 4, mr = lane & 15;
    int bm = blockIdx.y * 64, bn = blockIdx.x * 64;
    f32x4 acc[4];
    #pragma unroll
    for (int f = 0; f < 4; ++f) acc[f] = (f32x4){0.f, 0.f, 0.f, 0.f};
    for (int k0 = 0; k0 < K; k0 += 64) {
        #pragma unroll
        for (int i = 0; i < 2; ++i) {
            int c = tid + 256 * i;
            int r = c >> 3, c8 = (c & 7) * 8;
            *(short8*)&Al[r][c8] = *(const short8*)(A + (size_t)(bm + r) * K + k0 + c8);
        }
        #pragma unroll
        for (int i = 0; i < 2; ++i) {
            int c = tid + 256 * i;
            int r = c >> 3, c8 = (c & 7) * 8;
            *(short8*)&Bl[r][c8] = *(const short8*)(BT + (size_t)(bn + r) * K + k0 + c8);
        }
        __syncthreads();
        #pragma unroll
        for (int kk = 0; kk < 64; kk += 32) {
            short8 av = *(const short8*)&Al[16 * w + mr][kk + g * 8];
            #pragma unroll
            for (int f = 0; f < 4; ++f) {
                short8 bv = *(const short8*)&Bl[16 * f + mr][kk + g * 8];
                acc[f] = __builtin_amdgcn_mfma_f32_16x16x32_bf16(av, bv, acc[f], 0, 0, 0);
            }
        }
        __syncthreads();
    }
    #pragma unroll
    for (int f = 0; f < 4; ++f) {
        int col = bn + 16 * f + mr;
        float bv = bias[col];
        #pragma unroll
        for (int r = 0; r < 4; ++r) {
            int row = bm + 16 * w + 4 * g + r;
            Cb[(size_t)row * N + col] = f2bf(gelu_f(acc[f][r] + bv));
        }
    }
}

// ---- fused GEMM2+GEMM3, 64x64 tiles ----
// by<64: h = h1 @ pw2T^T + pb2 + emb[idx] (K=512)
// else : e_pre = enh @ fwT^T + ctail      (K=128; ctail includes fb + const tail)
__global__ __launch_bounds__(256) void k_mid(
    const ushort* __restrict__ h1, const ushort* __restrict__ pw2T,
    const float* __restrict__ pb2, const int* __restrict__ levels,
    const float* __restrict__ emb, float* __restrict__ h,
    const ushort* __restrict__ enh, const ushort* __restrict__ fwT,
    const float* __restrict__ ctail, float* __restrict__ e_pre) {
    __shared__ ushort Al[64][72];
    __shared__ ushort Bl[64][72];
    int by = blockIdx.y;
    const ushort* A; const ushort* BT; const float* bias; float* Cf;
    int K, sA, sB, epi, bm;
    if (by < 64) { A = h1; BT = pw2T; bias = pb2; Cf = h; K = DD2; sA = DD2; sB = DD2; epi = 2; bm = by * 64; }
    else         { A = enh; BT = fwT; bias = ctail; Cf = e_pre; K = DHH; sA = DHH; sB = DD; epi = 0; bm = (by - 64) * 64; }
    int tid = threadIdx.x;
    int w = tid >> 6, lane = tid & 63;
    int g = lane >> 4, mr = lane & 15;
    int bn = blockIdx.x * 64;
    f32x4 acc[4];
    #pragma unroll
    for (int f = 0; f < 4; ++f) acc[f] = (f32x4){0.f, 0.f, 0.f, 0.f};
    for (int k0 = 0; k0 < K; k0 += 64) {
        #pragma unroll
        for (int i = 0; i < 2; ++i) {
            int c = tid + 256 * i;
            int r = c >> 3, c8 = (c & 7) * 8;
            *(short8*)&Al[r][c8] = *(const short8*)(A + (size_t)(bm + r) * sA + k0 + c8);
        }
        #pragma unroll
        for (int i = 0; i < 2; ++i) {
            int c = tid + 256 * i;
            int r = c >> 3, c8 = (c & 7) * 8;
            *(short8*)&Bl[r][c8] = *(const short8*)(BT + (size_t)(bn + r) * sB + k0 + c8);
        }
        __syncthreads();
        #pragma unroll
        for (int kk = 0; kk < 64; kk += 32) {
            short8 av = *(const short8*)&Al[16 * w + mr][kk + g * 8];
            #pragma unroll
            for (int f = 0; f < 4; ++f) {
                short8 bv = *(const short8*)&Bl[16 * f + mr][kk + g * 8];
                acc[f] = __builtin_amdgcn_mfma_f32_16x16x32_bf16(av, bv, acc[f], 0, 0, 0);
            }
        }
        __syncthreads();
    }
    #pragma unroll
    for (int f = 0; f < 4; ++f) {
        int col = bn + 16 * f + mr;
        float bv = bias[col];
        #pragma unroll
        for (int r = 0; r < 4; ++r) {
            int row = bm + 16 * w + 4 * g + r;
            float v = acc[f][r] + bv;
            if (epi == 2) {
                int id = min(max(levels[row * 2], 0), NEXP - 1);
                v += emb[(size_t)id * DD + col];
            }
            Cf[(size_t)row * DD + col] = v;
        }
    }
}

// ---- fully fused adapter, 8 waves/block ----
__global__ __launch_bounds__(512) void k_adapterF(
    const float* __restrict__ h, const float* __restrict__ e_pre,
    const float* __restrict__ fg, const float* __restrict__ fbeta,
    const ushort* __restrict__ aWT, const float* __restrict__ ab,
    const float* __restrict__ ag, const float* __restrict__ abt,
    const ushort* __restrict__ dw1T, const float* __restrict__ db1,
    const float* __restrict__ dw2, const float* __restrict__ db2,
    const int* __restrict__ sorted, const int* __restrict__ tpos,
    const int* __restrict__ tcnt, const int* __restrict__ texp,
    const int* __restrict__ meta, float* __restrict__ out) {
    __shared__ __align__(16) ushort Alf[TM][264];       // hfull bf16, later y bf16
    __shared__ __align__(16) char BlRaw[256 * 72 * 2];  // Bl[256][72] then yf32[32][260]
    __shared__ __align__(16) ushort Dl[DHH][72];
    __shared__ int tokS[TM];
    __shared__ float gateS[TM];
    __shared__ float pg[4][TM];
    int b = blockIdx.x;
    if (b >= meta[0]) return;
    int tid = threadIdx.x, w = tid >> 6, lane = tid & 63;
    int g = lane >> 4, mr = lane & 15;
    int e = texp[b], base = tpos[b], nv = tcnt[b];
    if (tid < TM) tokS[tid] = sorted[base + min(tid, nv - 1)];
    __syncthreads();
    // phase 1: hfull = h + 0.3*gelu(LN(e_pre)) ; 8 waves x 4 rows
    #pragma unroll
    for (int i = 0; i < 4; ++i) {
        int r = w * 4 + i;
        int tok = tokS[r];
        float4 e4 = *(const float4*)(e_pre + (size_t)tok * DD + lane * 4);
        float s = e4.x + e4.y + e4.z + e4.w;
        float s2 = e4.x * e4.x + e4.y * e4.y + e4.z * e4.z + e4.w * e4.w;
        #pragma unroll
        for (int o = 1; o < 64; o <<= 1) { s += __shfl_xor(s, o); s2 += __shfl_xor(s2, o); }
        float m = s * (1.f / 256.f);
        float rs = rsqrtf(s2 * (1.f / 256.f) - m * m + 1e-5f);
        float4 h4 = *(const float4*)(h + (size_t)tok * DD + lane * 4);
        float4 g4 = *(const float4*)(fg + lane * 4);
        float4 b4 = *(const float4*)(fbeta + lane * 4);
        ushort4 o4;
        o4.x = f2bf(h4.x + 0.3f * gelu_f((e4.x - m) * rs * g4.x + b4.x));
        o4.y = f2bf(h4.y + 0.3f * gelu_f((e4.y - m) * rs * g4.y + b4.y));
        o4.z = f2bf(h4.z + 0.3f * gelu_f((e4.z - m) * rs * g4.z + b4.z));
        o4.w = f2bf(h4.w + 0.3f * gelu_f((e4.w - m) * rs * g4.w + b4.w));
        *(ushort4*)&Alf[r][lane * 4] = o4;
    }
    __syncthreads();
    // phase 2: expert GEMM [32x256]; wave w: row-frag (w&1), col base 64*(w>>1)
    ushort* Bl = (ushort*)BlRaw;
    const ushort* We = aWT + (size_t)e * DD * DD;
    int mt = w & 1, cb = 64 * (w >> 1);
    f32x4 acc[4];
    #pragma unroll
    for (int t = 0; t < 4; ++t) acc[t] = (f32x4){0.f, 0.f, 0.f, 0.f};
    for (int k0 = 0; k0 < DD; k0 += 64) {
        #pragma unroll
        for (int i = 0; i < 4; ++i) {
            int c = tid + 512 * i;
            int r = c >> 3, c8 = (c & 7) * 8;
            *(short8*)&Bl[r * 72 + c8] = *(const short8*)(We + (size_t)r * DD + k0 + c8);
        }
        __syncthreads();
        #pragma unroll
        for (int kk = 0; kk < 64; kk += 32) {
            short8 av = *(const short8*)&Alf[16 * mt + mr][k0 + kk + g * 8];
            #pragma unroll
            for (int t = 0; t < 4; ++t) {
                short8 bv = *(const short8*)&Bl[(cb + 16 * t + mr) * 72 + kk + g * 8];
                acc[t] = __builtin_amdgcn_mfma_f32_16x16x32_bf16(av, bv, acc[t], 0, 0, 0);
            }
        }
        __syncthreads();
    }
    // phase 3: yf32 = acc + ab
    float* yf32 = (float*)BlRaw;
    #pragma unroll
    for (int t = 0; t < 4; ++t) {
        int col = cb + 16 * t + mr;
        float abv = ab[(size_t)e * DD + col];
        #pragma unroll
        for (int r = 0; r < 4; ++r) {
            int row = 16 * mt + 4 * g + r;
            yf32[row * 260 + col] = acc[t][r] + abv;
        }
    }
    __syncthreads();
    // phase 4: per-row LN(ag,abt)+gelu; write yf32 + bf16 Alf
    #pragma unroll
    for (int i = 0; i < 4; ++i) {
        int r = w * 4 + i;
        float4 v = *(const float4*)&yf32[r * 260 + lane * 4];
        float s = v.x + v.y + v.z + v.w;
        float s2 = v.x * v.x + v.y * v.y + v.z * v.z + v.w * v.w;
        #pragma unroll
        for (int o = 1; o < 64; o <<= 1) { s += __shfl_xor(s, o); s2 += __shfl_xor(s2, o); }
        float m = s * (1.f / 256.f);
        float rs = rsqrtf(s2 * (1.f / 256.f) - m * m + 1e-5f);
        float4 gg = *(const float4*)(ag + (size_t)e * DD + lane * 4);
        float4 bb = *(const float4*)(abt + (size_t)e * DD + lane * 4);
        float4 y;
        y.x = gelu_f((v.x - m) * rs * gg.x + bb.x);
        y.y = gelu_f((v.y - m) * rs * gg.y + bb.y);
        y.z = gelu_f((v.z - m) * rs * gg.z + bb.z);
        y.w = gelu_f((v.w - m) * rs * gg.w + bb.w);
        *(float4*)&yf32[r * 260 + lane * 4] = y;
        ushort4 o4 = {f2bf(y.x), f2bf(y.y), f2bf(y.z), f2bf(y.w)};
        *(ushort4*)&Alf[r][lane * 4] = o4;
    }
    __syncthreads();
    // phase 5: gate GEMM [32x128] = ybf @ dw1T^T; wave w: row-frag (w&1), col-frags 2*(w>>1)+{0,1}
    f32x4 acc2[2];
    acc2[0] = (f32x4){0.f, 0.f, 0.f, 0.f};
    acc2[1] = (f32x4){0.f, 0.f, 0.f, 0.f};
    for (int k0 = 0; k0 < DD; k0 += 64) {
        #pragma unroll
        for (int i = 0; i < 2; ++i) {
            int c = tid + 512 * i;
            int r = c >> 3, c8 = (c & 7) * 8;
            *(short8*)&Dl[r][c8] = *(const short8*)(dw1T + (size_t)r * DD + k0 + c8);
        }
        __syncthreads();
        #pragma unroll
        for (int kk = 0; kk < 64; kk += 32) {
            short8 av = *(const short8*)&Alf[16 * mt + mr][k0 + kk + g * 8];
            #pragma unroll
            for (int t = 0; t < 2; ++t) {
                short8 bv = *(const short8*)&Dl[16 * (2 * (w >> 1) + t) + mr][kk + g * 8];
                acc2[t] = __builtin_amdgcn_mfma_f32_16x16x32_bf16(av, bv, acc2[t], 0, 0, 0);
            }
        }
        __syncthreads();
    }
    // phase 6: p[row] = sum_col relu(g+db1)*dw2
    float pv[4] = {0.f, 0.f, 0.f, 0.f};
    #pragma unroll
    for (int t = 0; t < 2; ++t) {
        int col = 32 * (w >> 1) + 16 * t + mr;
        float d1 = db1[col], d2 = dw2[col];
        #pragma unroll
        for (int r = 0; r < 4; ++r)
            pv[r] += fmaxf(acc2[t][r] + d1, 0.f) * d2;
    }
    #pragma unroll
    for (int o = 1; o < 16; o <<= 1) {
        #pragma unroll
        for (int r = 0; r < 4; ++r) pv[r] += __shfl_xor(pv[r], o);
    }
    if (mr == 0) {
        #pragma unroll
        for (int r = 0; r < 4; ++r)
            pg[w >> 1][16 * mt + 4 * g + r] = pv[r];
    }
    __syncthreads();
    if (tid < TM) {
        float p = pg[0][tid] + pg[1][tid] + pg[2][tid] + pg[3][tid] + db2[0];
        gateS[tid] = 0.8f + 0.4f / (1.f + expf(-p));
    }
    __syncthreads();
    // phase 7: scatter out = y * gate ; 512 threads: 32 rows x 16 segs of 16
    {
        int row = tid >> 4, c0 = (tid & 15) * 16;
        if (row < nv) {
            int tok = tokS[row];
            float gt = gateS[row];
            #pragma unroll
            for (int j = 0; j < 4; ++j) {
                float4 v = *(const float4*)&yf32[row * 260 + c0 + j * 4];
                v.x *= gt; v.y *= gt; v.z *= gt; v.w *= gt;
                *(float4*)(out + (size_t)tok * DD + c0 + j * 4) = v;
            }
        }
    }
}

extern "C" void kernel_launch(void* const* d_in, const int* in_sizes, int n_in,
                              void* d_out, int out_size, void* d_ws, size_t ws_size,
                              hipStream_t stream) {
    const float* tokens = (const float*)d_in[0];
    const float* ln_g = (const float*)d_in[1];
    const float* ln_b = (const float*)d_in[2];
    const float* pw1 = (const float*)d_in[3];
    const float* pb1 = (const float*)d_in[4];
    const float* pw2 = (const float*)d_in[5];
    const float* pb2 = (const float*)d_in[6];
    const float* emb = (const float*)d_in[7];
    const float* sw1 = (const float*)d_in[8];
    const float* sb1 = (const float*)d_in[9];
    const float* sw2 = (const float*)d_in[10];
    const float* sb2 = (const float*)d_in[11];
    const float* ew1 = (const float*)d_in[12];
    const float* eb1 = (const float*)d_in[13];
    const float* ew2 = (const float*)d_in[14];
    const float* eb2 = (const float*)d_in[15];
    const float* spw1 = (const float*)d_in[16];
    const float* spb1 = (const float*)d_in[17];
    const float* spw2 = (const float*)d_in[18];
    const float* spb2 = (const float*)d_in[19];
    const float* lw1 = (const float*)d_in[20];
    const float* lb1 = (const float*)d_in[21];
    const float* lw2 = (const float*)d_in[22];
    const float* lb2 = (const float*)d_in[23];
    const float* fw = (const float*)d_in[24];
    const float* fb = (const float*)d_in[25];
    const float* fg = (const float*)d_in[26];
    const float* fbeta = (const float*)d_in[27];
    const float* aW = (const float*)d_in[28];
    const float* ab = (const float*)d_in[29];
    const float* ag = (const float*)d_in[30];
    const float* abt = (const float*)d_in[31];
    const float* dw1 = (const float*)d_in[32];
    const float* db1 = (const float*)d_in[33];
    const float* dw2 = (const float*)d_in[34];
    const float* db2 = (const float*)d_in[35];
    const int* levels = (const int*)d_in[36];
    const int* ph = (const int*)d_in[37];
    const int* pw = (const int*)d_in[38];
    float* outp = (float*)d_out;

    char* wsb = (char*)d_ws;
    ushort* x_ln  = (ushort*)wsb;  wsb += (size_t)NTOK * IND * 2;
    ushort* h1    = (ushort*)wsb;  wsb += (size_t)NTOK * DD2 * 2;
    ushort* enh   = (ushort*)wsb;  wsb += (size_t)NTOK * DHH * 2;
    float*  h     = (float*)wsb;   wsb += (size_t)NTOK * DD * 4;
    float*  e_pre = (float*)wsb;   wsb += (size_t)NTOK * DD * 4;
    ushort* pw1T  = (ushort*)wsb;  wsb += (size_t)DD2 * IND * 2;
    ushort* pw2T  = (ushort*)wsb;  wsb += (size_t)DD * DD2 * 2;
    ushort* fwT   = (ushort*)wsb;  wsb += (size_t)DD * DD * 2;
    ushort* aWT   = (ushort*)wsb;  wsb += (size_t)NEXP * DD * DD * 2;
    ushort* dw1T  = (ushort*)wsb;  wsb += (size_t)DHH * DD * 2;
    float*  ctail = (float*)wsb;   wsb += DD * 4;
    int*    sorted = (int*)wsb;    wsb += NTOK * 4;
    int*    tpos   = (int*)wsb;    wsb += NTILE_MAX * 4 + 4;
    int*    tcnt   = (int*)wsb;    wsb += NTILE_MAX * 4 + 4;
    int*    texp   = (int*)wsb;    wsb += NTILE_MAX * 4 + 4;
    int*    meta   = (int*)wsb;    wsb += 64;

    k_pre<<<1 + NWCONV + NTOK, 256, 0, stream>>>(
        pw1, pw2, fw, dw1, aW, pw1T, pw2T, fwT, dw1T, aWT,
        tokens, ln_g, ln_b, sw1, sb1, sw2, sb2, ew1, eb1, ew2, eb2,
        x_ln, enh, levels,
        spw1, spb1, spw2, spb2, lw1, lb1, lw2, lb2, ph, pw, fb,
        sorted, tpos, tcnt, texp, meta, ctail);
    k_gemm1<<<dim3(DD2 / 64, NTOK / 64), 256, 0, stream>>>(x_ln, pw1T, pb1, h1);
    k_mid<<<dim3(DD / 64, 128), 256, 0, stream>>>(
        h1, pw2T, pb2, levels, emb, h, enh, fwT, ctail, e_pre);
    k_adapterF<<<NTILE_MAX, 512, 0, stream>>>(
        h, e_pre, fg, fbeta, aWT, ab, ag, abt, dw1T, db1, dw2, db2,
        sorted, tpos, tcnt, texp, meta, outp);
}